// Round 5
// baseline (585.423 us; speedup 1.0000x reference)
//
#include <hip/hip_runtime.h>
#include <hip/hip_bf16.h>
#include <stdint.h>

typedef __attribute__((ext_vector_type(8))) short short8;
typedef __attribute__((ext_vector_type(4))) float f32x4;
typedef __attribute__((ext_vector_type(16))) float f32x16;
typedef unsigned short u16;

#define B_  2
#define T_  2048
#define D_  1024
#define H_  16
#define DH_ 64
#define NSPLIT 2
#define KVSPAN (T_ / NSPLIT)

__device__ __forceinline__ u16 f2bf(float x) {
    union { float f; uint32_t u; } v; v.f = x;
    uint32_t r = v.u + 0x7fffu + ((v.u >> 16) & 1u);
    return (u16)(r >> 16);
}
__device__ __forceinline__ float bf2f(u16 h) {
    union { uint32_t u; float f; } v; v.u = ((uint32_t)h) << 16;
    return v.f;
}
__device__ __forceinline__ f32x4 mfma16(short8 a, short8 b, f32x4 c) {
    return __builtin_amdgcn_mfma_f32_16x16x32_bf16(a, b, c, 0, 0, 0);
}
__device__ __forceinline__ f32x16 mfma32(short8 a, short8 b, f32x16 c) {
    return __builtin_amdgcn_mfma_f32_32x32x16_bf16(a, b, c, 0, 0, 0);
}
__device__ __forceinline__ void gload16(const u16* g, u16* l) {
    __builtin_amdgcn_global_load_lds(
        (const __attribute__((address_space(1))) uint32_t*)g,
        (__attribute__((address_space(3))) uint32_t*)l, 16, 0, 0);
}

// ---------------------------------------------------------------------------
// Kernel 0: pack int32 mask -> bit mask (1 MB, L2-resident in attn).
// ---------------------------------------------------------------------------
__global__ __launch_bounds__(256) void maskpack_kernel(
    const int* __restrict__ mask, uint32_t* __restrict__ bits)
{
    size_t e = (size_t)blockIdx.x * 256 + threadIdx.x;
    unsigned long long b = __ballot(mask[e] != 0);
    if ((threadIdx.x & 63) == 0)
        *(unsigned long long*)(bits + (e >> 5)) = b;
}

// ---------------------------------------------------------------------------
// Kernel 0b: split X fp32 -> Xhi/Xlo bf16 (one-time conversion).
// ---------------------------------------------------------------------------
__global__ __launch_bounds__(256) void splitx_kernel(
    const float* __restrict__ X, u16* __restrict__ Xhi, u16* __restrict__ Xlo)
{
    size_t i0 = ((size_t)blockIdx.x * 256 + threadIdx.x) * 8;
    float4 a = *(const float4*)(X + i0);
    float4 b = *(const float4*)(X + i0 + 4);
    float v[8] = {a.x, a.y, a.z, a.w, b.x, b.y, b.z, b.w};
    union { u16 h[8]; short8 s; } Hh, Ll;
#pragma unroll
    for (int i = 0; i < 8; ++i) {
        Hh.h[i] = f2bf(v[i]);
        Ll.h[i] = f2bf(v[i] - bf2f(Hh.h[i]));
    }
    *(short8*)(Xhi + i0) = Hh.s;
    *(short8*)(Xlo + i0) = Ll.s;
}

// ---------------------------------------------------------------------------
// Kernel 0c: transpose + split weights.  W[k][n] fp32 -> WT[n][k] bf16.
// ---------------------------------------------------------------------------
__global__ __launch_bounds__(256) void wtr_kernel(
    const float* __restrict__ Wq, const float* __restrict__ Wk,
    const float* __restrict__ Wv, const float* __restrict__ Wo,
    u16* __restrict__ WqThi, u16* __restrict__ WqTlo,
    u16* __restrict__ WkThi, u16* __restrict__ WkTlo,
    u16* __restrict__ WvT,   u16* __restrict__ WoT)
{
    __shared__ float s_t[64][65];
    const int zz = blockIdx.z;
    const float* __restrict__ W = (zz == 0) ? Wq : (zz == 1) ? Wk : (zz == 2) ? Wv : Wo;
    const int k0 = blockIdx.y * 64, n0 = blockIdx.x * 64;
    const int t = threadIdx.x;
    const int r = t >> 2, c0 = (t & 3) * 16;

#pragma unroll
    for (int j = 0; j < 4; ++j) {
        float4 v = *(const float4*)(W + (size_t)(k0 + r) * D_ + n0 + c0 + j * 4);
        s_t[r][c0 + j * 4 + 0] = v.x;
        s_t[r][c0 + j * 4 + 1] = v.y;
        s_t[r][c0 + j * 4 + 2] = v.z;
        s_t[r][c0 + j * 4 + 3] = v.w;
    }
    __syncthreads();

    const int n = t >> 2, kc = (t & 3) * 16;
    union { u16 h[16]; short8 s[2]; } Hh, Ll;
#pragma unroll
    for (int j = 0; j < 16; ++j) {
        float x = s_t[kc + j][n];
        Hh.h[j] = f2bf(x);
        Ll.h[j] = f2bf(x - bf2f(Hh.h[j]));
    }
    u16* dh = (zz == 0) ? WqThi : (zz == 1) ? WkThi : (zz == 2) ? WvT : WoT;
    u16* dl = (zz == 0) ? WqTlo : (zz == 1) ? WkTlo : nullptr;
    size_t o = (size_t)(n0 + n) * D_ + k0 + kc;
    *(short8*)(dh + o) = Hh.s[0];
    *(short8*)(dh + o + 8) = Hh.s[1];
    if (dl) {
        *(short8*)(dl + o) = Ll.s[0];
        *(short8*)(dl + o + 8) = Ll.s[1];
    }
}

// ---------------------------------------------------------------------------
// Kernel 1: m97-style 128x128 GEMM, BK=32, global_load_lds staging.
// z: 0=Q (split out, *1/8)  1=K (split out)  2=V (bf16, [B,H,64,T])  3=O (fp32)
// ---------------------------------------------------------------------------
__global__ __launch_bounds__(256) void gemm_kernel(
    const u16* __restrict__ Ahi, const u16* __restrict__ Alo, int zbase,
    const u16* __restrict__ BqH, const u16* __restrict__ BqL,
    const u16* __restrict__ BkH, const u16* __restrict__ BkL,
    const u16* __restrict__ BvT, const u16* __restrict__ BoT,
    const float* __restrict__ bq, const float* __restrict__ bk,
    const float* __restrict__ bv, const float* __restrict__ bo,
    u16* __restrict__ Qhi, u16* __restrict__ Qlo,
    u16* __restrict__ Khi, u16* __restrict__ Klo,
    u16* __restrict__ Vt,  float* __restrict__ outF)
{
    __shared__ u16 sAhi[128 * 32];
    __shared__ u16 sAlo[128 * 32];
    __shared__ u16 sBhi[128 * 32];
    __shared__ u16 sBlo[128 * 32];

    const int z = blockIdx.z + zbase;
    const u16* __restrict__ Bh = (z == 0) ? BqH : (z == 1) ? BkH : (z == 2) ? BvT : BoT;
    const u16* __restrict__ Bl = (z == 0) ? BqL : (z == 1) ? BkL : nullptr;
    const float* __restrict__ bias = (z == 0) ? bq : (z == 1) ? bk : (z == 2) ? bv : bo;
    const bool split = (z < 2);

    const int m0 = blockIdx.y * 128;
    const int n0 = blockIdx.x * 128;
    const int tid = threadIdx.x;
    const int w = tid >> 6, l = tid & 63;
    const int g = l >> 4, lr = l & 15;
    const int wm = w >> 1, wn = w & 1;

    const int srow = w * 32 + (l >> 2);
    const int skb  = (l & 3) * 8;

    f32x4 acc[4][4] = {};

    for (int k0 = 0; k0 < D_; k0 += 32) {
        __syncthreads();
#pragma unroll
        for (int i = 0; i < 2; ++i) {
            gload16(Ahi + (size_t)(m0 + srow + i * 16) * D_ + k0 + skb,
                    &sAhi[w * 1024 + i * 512]);
            gload16(Bh + (size_t)(n0 + srow + i * 16) * D_ + k0 + skb,
                    &sBhi[w * 1024 + i * 512]);
        }
        if (split) {
#pragma unroll
            for (int i = 0; i < 2; ++i) {
                gload16(Alo + (size_t)(m0 + srow + i * 16) * D_ + k0 + skb,
                        &sAlo[w * 1024 + i * 512]);
                gload16(Bl + (size_t)(n0 + srow + i * 16) * D_ + k0 + skb,
                        &sBlo[w * 1024 + i * 512]);
            }
        }
        __syncthreads();

        short8 ah[4], bh[4];
#pragma unroll
        for (int f = 0; f < 4; ++f) {
            ah[f] = *(const short8*)&sAhi[(wm * 64 + f * 16 + lr) * 32 + g * 8];
            bh[f] = *(const short8*)&sBhi[(wn * 64 + f * 16 + lr) * 32 + g * 8];
        }
#pragma unroll
        for (int fm = 0; fm < 4; ++fm)
#pragma unroll
            for (int fn = 0; fn < 4; ++fn)
                acc[fm][fn] = mfma16(ah[fm], bh[fn], acc[fm][fn]);
        if (split) {
            short8 al[4], bl[4];
#pragma unroll
            for (int f = 0; f < 4; ++f) {
                al[f] = *(const short8*)&sAlo[(wm * 64 + f * 16 + lr) * 32 + g * 8];
                bl[f] = *(const short8*)&sBlo[(wn * 64 + f * 16 + lr) * 32 + g * 8];
            }
#pragma unroll
            for (int fm = 0; fm < 4; ++fm)
#pragma unroll
                for (int fn = 0; fn < 4; ++fn) {
                    acc[fm][fn] = mfma16(ah[fm], bl[fn], acc[fm][fn]);
                    acc[fm][fn] = mfma16(al[fm], bh[fn], acc[fm][fn]);
                }
        }
    }

    const float scale = (z == 0) ? 0.125f : 1.0f;
    float biasv[4];
#pragma unroll
    for (int f = 0; f < 4; ++f) biasv[f] = bias[n0 + wn * 64 + f * 16 + lr];

    if (z <= 1) {
        u16* Oh = (z == 0) ? Qhi : Khi;
        u16* Ol = (z == 0) ? Qlo : Klo;
#pragma unroll
        for (int fm = 0; fm < 4; ++fm)
#pragma unroll
            for (int fn = 0; fn < 4; ++fn)
#pragma unroll
                for (int j = 0; j < 4; ++j) {
                    int r = m0 + wm * 64 + fm * 16 + g * 4 + j;
                    int c = n0 + wn * 64 + fn * 16 + lr;
                    float v = (acc[fm][fn][j] + biasv[fn]) * scale;
                    int b = r >> 11, t = r & (T_ - 1);
                    int h = (c >> 6) & 15, d = c & 63;
                    size_t idx = ((size_t)(b * H_ + h) * T_ + t) * DH_ + d;
                    u16 hv = f2bf(v);
                    Oh[idx] = hv;
                    Ol[idx] = f2bf(v - bf2f(hv));
                }
    } else if (z == 2) {
#pragma unroll
        for (int fm = 0; fm < 4; ++fm)
#pragma unroll
            for (int fn = 0; fn < 4; ++fn) {
                int r0 = m0 + wm * 64 + fm * 16 + g * 4;
                int c  = n0 + wn * 64 + fn * 16 + lr;
                int b = r0 >> 11, t0 = r0 & (T_ - 1);
                int h = (c >> 6) & 15, d = c & 63;
                uint2 pk;
                pk.x = (uint32_t)f2bf(acc[fm][fn][0] + biasv[fn]) |
                       ((uint32_t)f2bf(acc[fm][fn][1] + biasv[fn]) << 16);
                pk.y = (uint32_t)f2bf(acc[fm][fn][2] + biasv[fn]) |
                       ((uint32_t)f2bf(acc[fm][fn][3] + biasv[fn]) << 16);
                *(uint2*)&Vt[((size_t)(b * H_ + h) * DH_ + d) * T_ + t0] = pk;
            }
    } else {
#pragma unroll
        for (int fm = 0; fm < 4; ++fm)
#pragma unroll
            for (int fn = 0; fn < 4; ++fn)
#pragma unroll
                for (int j = 0; j < 4; ++j) {
                    int r = m0 + wm * 64 + fm * 16 + g * 4 + j;
                    int c = n0 + wn * 64 + fn * 16 + lr;
                    outF[(size_t)r * D_ + c] = acc[fm][fn][j] + biasv[fn];
                }
    }
}

// ---------------------------------------------------------------------------
// Kernel 2: flash attention, swapped-QK^T 32x32x16, KV-SPLIT x2 across blocks
// (grid 1024 -> 4 waves/SIMD), register double-buffer, tree reductions,
// XCD swizzle keeping all 32 (qb,sp) blocks of one (b,h) on one XCD.
// Writes normalized partial O (bf16) + (m,l) stats per split.
// ---------------------------------------------------------------------------
__device__ __forceinline__ void attn_tile(
    const short8* kh, const short8* kl, const short8* vb, uint32_t mw,
    const short8* qfh, const short8* qfl,
    f32x16& o0, f32x16& o1, float& m_run, float& l_run)
{
    const float L2E = 1.4426950408889634f;
    f32x16 s = {};
    __builtin_amdgcn_s_setprio(1);
#pragma unroll
    for (int c = 0; c < 4; ++c) {
        s = mfma32(kh[c], qfh[c], s);
        s = mfma32(kh[c], qfl[c], s);
        s = mfma32(kl[c], qfh[c], s);
    }
    __builtin_amdgcn_s_setprio(0);

#pragma unroll
    for (int r = 0; r < 16; ++r) {
        const int bit = (r & 3) + 8 * (r >> 2);
        if (!((mw >> bit) & 1u)) s[r] = -1e30f;
    }

    // tree row-max (depth 4 + cross-half)
    float t8[8], t4[4], t2[2];
#pragma unroll
    for (int i = 0; i < 8; ++i) t8[i] = fmaxf(s[i], s[i + 8]);
#pragma unroll
    for (int i = 0; i < 4; ++i) t4[i] = fmaxf(t8[i], t8[i + 4]);
    t2[0] = fmaxf(t4[0], t4[2]); t2[1] = fmaxf(t4[1], t4[3]);
    float pm = fmaxf(t2[0], t2[1]);
    pm = fmaxf(pm, __shfl_xor(pm, 32));

    if (__any(pm > m_run + 8.0f)) {        // defer-max rescale (T13)
        float mn  = fmaxf(m_run, pm);
        float fac = exp2f((m_run - mn) * L2E);
        l_run *= fac;
#pragma unroll
        for (int r = 0; r < 16; ++r) { o0[r] *= fac; o1[r] *= fac; }
        m_run = mn;
    }

    float p[16];
#pragma unroll
    for (int r = 0; r < 16; ++r) p[r] = exp2f((s[r] - m_run) * L2E);
    // tree row-sum
    float a8[8], a4[4], a2[2];
#pragma unroll
    for (int i = 0; i < 8; ++i) a8[i] = p[i] + p[i + 8];
#pragma unroll
    for (int i = 0; i < 4; ++i) a4[i] = a8[i] + a8[i + 4];
    a2[0] = a4[0] + a4[2]; a2[1] = a4[1] + a4[3];
    float sum = a2[0] + a2[1];
    sum += __shfl_xor(sum, 32);
    l_run += sum;

    uint32_t wv[8];
#pragma unroll
    for (int m2 = 0; m2 < 8; ++m2)
        asm("v_cvt_pk_bf16_f32 %0, %1, %2"
            : "=v"(wv[m2]) : "v"(p[2 * m2]), "v"(p[2 * m2 + 1]));
    asm("v_permlane32_swap_b32 %0, %1" : "+v"(wv[0]), "+v"(wv[2]));
    asm("v_permlane32_swap_b32 %0, %1" : "+v"(wv[1]), "+v"(wv[3]));
    asm("v_permlane32_swap_b32 %0, %1" : "+v"(wv[4]), "+v"(wv[6]));
    asm("v_permlane32_swap_b32 %0, %1" : "+v"(wv[5]), "+v"(wv[7]));
    union { uint32_t u[4]; short8 s8; } pa1, pa2;
    pa1.u[0] = wv[0]; pa1.u[1] = wv[1]; pa1.u[2] = wv[2]; pa1.u[3] = wv[3];
    pa2.u[0] = wv[4]; pa2.u[1] = wv[5]; pa2.u[2] = wv[6]; pa2.u[3] = wv[7];

    __builtin_amdgcn_s_setprio(1);
    o0 = mfma32(vb[0], pa1.s8, o0);
    o0 = mfma32(vb[1], pa2.s8, o0);
    o1 = mfma32(vb[2], pa1.s8, o1);
    o1 = mfma32(vb[3], pa2.s8, o1);
    __builtin_amdgcn_s_setprio(0);
}

#define LOAD_TILE(kh, kl, vb, mw, kv)                                          \
    do {                                                                       \
        _Pragma("unroll")                                                      \
        for (int c = 0; c < 4; ++c) {                                          \
            kh[c] = *(const short8*)&Kh[(size_t)((kv) + qi) * DH_ + c * 16 + hl * 8]; \
            kl[c] = *(const short8*)&Kl[(size_t)((kv) + qi) * DH_ + c * 16 + hl * 8]; \
        }                                                                      \
        vb[0] = *(const short8*)&Vh[(size_t)(qi) * T_ + (kv) + hl * 8];        \
        vb[1] = *(const short8*)&Vh[(size_t)(qi) * T_ + (kv) + 16 + hl * 8];   \
        vb[2] = *(const short8*)&Vh[(size_t)(32 + qi) * T_ + (kv) + hl * 8];   \
        vb[3] = *(const short8*)&Vh[(size_t)(32 + qi) * T_ + (kv) + 16 + hl * 8]; \
        mw = mrow[(kv) >> 5] >> (hl * 4);                                      \
    } while (0)

__global__ __launch_bounds__(256, 4) void attn_split_kernel(
    const u16* __restrict__ Qhi, const u16* __restrict__ Qlo,
    const u16* __restrict__ Khi, const u16* __restrict__ Klo,
    const u16* __restrict__ Vt,  const uint32_t* __restrict__ bits,
    u16* __restrict__ Op0, u16* __restrict__ Op1,
    float2* __restrict__ stats)
{
    // bx = (hi<<8)|(mid<<3)|lo ; bh = lo|(hi<<3) -> all 32 (qb,sp) blocks of
    // one bh share bx%8 => same XCD under round-robin dispatch.
    const int bx  = blockIdx.x;
    const int bh  = (bx & 7) | ((bx >> 8) << 3);
    const int mid = (bx >> 3) & 31;
    const int qb  = mid >> 1;
    const int sp  = mid & 1;
    const int b   = bh >> 4, h = bh & 15;
    const int tid = threadIdx.x;
    const int w   = tid >> 6;
    const int l   = tid & 63;
    const int qi  = l & 31;
    const int hl  = l >> 5;
    const int q   = qb * 128 + w * 32 + qi;
    const int kvbase = sp * KVSPAN;

    const size_t hoff = (size_t)(b * H_ + h) * T_ * DH_;
    const u16* Qh = Qhi + hoff;
    const u16* Ql = Qlo + hoff;
    const u16* Kh = Khi + hoff;
    const u16* Kl = Klo + hoff;
    const u16* Vh = Vt  + hoff;                        // [64][T]
    const uint32_t* mrow = bits + ((size_t)b * T_ + q) * (T_ / 32);

    short8 qfh[4], qfl[4];
#pragma unroll
    for (int c = 0; c < 4; ++c) {
        qfh[c] = *(const short8*)&Qh[(size_t)q * DH_ + c * 16 + hl * 8];
        qfl[c] = *(const short8*)&Ql[(size_t)q * DH_ + c * 16 + hl * 8];
    }

    f32x16 o0 = {}; f32x16 o1 = {};
    float m_run = -1e30f, l_run = 0.0f;

    short8 khA[4], klA[4], vbA[4]; uint32_t mwA;
    short8 khB[4], klB[4], vbB[4]; uint32_t mwB;

    LOAD_TILE(khA, klA, vbA, mwA, kvbase);

    for (int kv0 = kvbase; kv0 < kvbase + KVSPAN; kv0 += 64) {
        LOAD_TILE(khB, klB, vbB, mwB, kv0 + 32);
        attn_tile(khA, klA, vbA, mwA, qfh, qfl, o0, o1, m_run, l_run);
        LOAD_TILE(khA, klA, vbA, mwA,
                  kvbase + ((kv0 + 64 - kvbase) & (KVSPAN - 1)));  // wraps
        attn_tile(khB, klB, vbB, mwB, qfh, qfl, o0, o1, m_run, l_run);
    }

    // epilogue: normalized partial O -> Op[sp], stats (m,l) -> stats[sp]
    float inv = 1.0f / l_run;
    float ov[32];
#pragma unroll
    for (int r = 0; r < 16; ++r) { ov[r] = o0[r]; ov[16 + r] = o1[r]; }
    u16* Op = (sp == 0) ? Op0 : Op1;
    u16* prow = Op + ((size_t)bh * T_ + q) * DH_;
#pragma unroll
    for (int dt = 0; dt < 2; ++dt)
#pragma unroll
        for (int g2 = 0; g2 < 4; ++g2) {
            float v0 = ov[dt * 16 + 4 * g2 + 0] * inv;
            float v1 = ov[dt * 16 + 4 * g2 + 1] * inv;
            float v2 = ov[dt * 16 + 4 * g2 + 2] * inv;
            float v3 = ov[dt * 16 + 4 * g2 + 3] * inv;
            uint2 pkt;
            pkt.x = (uint32_t)f2bf(v0) | ((uint32_t)f2bf(v1) << 16);
            pkt.y = (uint32_t)f2bf(v2) | ((uint32_t)f2bf(v3) << 16);
            *(uint2*)(prow + dt * 32 + 8 * g2 + 4 * hl) = pkt;
        }
    if (hl == 0)
        stats[(size_t)sp * (32 * T_) + (size_t)bh * T_ + q] =
            make_float2(m_run, l_run);
}

// ---------------------------------------------------------------------------
// Kernel 2b: combine the two KV-split partials -> comb (bf16 [B,T,D]).
// O = (w0*O0 + w1*O1)/(w0+w1), w_i = l_i * exp2((m_i - m)*log2e).
// ---------------------------------------------------------------------------
__global__ __launch_bounds__(256) void combine_kernel(
    const u16* __restrict__ Op0, const u16* __restrict__ Op1,
    const float2* __restrict__ stats, u16* __restrict__ comb)
{
    const float L2E = 1.4426950408889634f;
    const int row = blockIdx.x * 32 + (threadIdx.x >> 3);   // [0, 32*T_)
    const int dh0 = (threadIdx.x & 7) * 8;
    const int bh = row >> 11, q = row & (T_ - 1);
    const int b = bh >> 4, h = bh & 15;

    float2 s0 = stats[row];
    float2 s1 = stats[32 * T_ + row];
    float m = fmaxf(s0.x, s1.x);
    float w0 = s0.y * exp2f((s0.x - m) * L2E);
    float w1 = s1.y * exp2f((s1.x - m) * L2E);
    float rs = 1.0f / (w0 + w1);
    float a0 = w0 * rs, a1 = w1 * rs;

    union { short8 s; u16 h[8]; } v0, v1, ou;
    v0.s = *(const short8*)(Op0 + (size_t)row * DH_ + dh0);
    v1.s = *(const short8*)(Op1 + (size_t)row * DH_ + dh0);
#pragma unroll
    for (int i = 0; i < 8; ++i)
        ou.h[i] = f2bf(a0 * bf2f(v0.h[i]) + a1 * bf2f(v1.h[i]));
    *(short8*)(comb + ((size_t)(b * T_ + q)) * D_ + h * DH_ + dh0) = ou.s;
}

// ---------------------------------------------------------------------------
extern "C" void kernel_launch(void* const* d_in, const int* in_sizes, int n_in,
                              void* d_out, int out_size, void* d_ws, size_t ws_size,
                              hipStream_t stream)
{
    const float* X    = (const float*)d_in[0];
    const int*   mask = (const int*)d_in[1];
    const float* Wq   = (const float*)d_in[2];
    const float* bq   = (const float*)d_in[3];
    const float* Wk   = (const float*)d_in[4];
    const float* bk   = (const float*)d_in[5];
    const float* Wv   = (const float*)d_in[6];
    const float* bv   = (const float*)d_in[7];
    const float* Wo   = (const float*)d_in[8];
    const float* bo   = (const float*)d_in[9];
    float* out = (float*)d_out;

    const size_t SEG = (size_t)B_ * H_ * T_ * DH_;   // = B*T*D elems
    const size_t WSEG = (size_t)D_ * D_;
    u16* wsp = (u16*)d_ws;
    u16* Qhi   = wsp + 0 * SEG;
    u16* Qlo   = wsp + 1 * SEG;
    u16* Khi   = wsp + 2 * SEG;
    u16* Klo   = wsp + 3 * SEG;
    u16* Xhi   = wsp + 4 * SEG;        // comb aliases Xhi after QKV GEMM
    u16* Xlo   = wsp + 5 * SEG;        // Op0 aliases Xlo after QKV GEMM
    u16* WqThi = wsp + 6 * SEG;        // Op1 aliases WqT/WkT after QKV GEMM
    u16* WqTlo = WqThi + WSEG;
    u16* WkThi = WqThi + 2 * WSEG;
    u16* WkTlo = WqThi + 3 * WSEG;
    u16* WvT   = WqThi + 4 * WSEG;
    u16* WoT   = WqThi + 5 * WSEG;
    u16* comb  = Xhi;
    u16* Op0   = Xlo;
    u16* Op1   = WqThi;
    // d_out scratch: Vt (8 MiB) + bits (1 MiB) + stats (1 MiB); final GEMM
    // overwrites all of d_out.
    u16* Vt = (u16*)d_out;
    uint32_t* bits = (uint32_t*)((char*)d_out + (8u << 20));
    float2* stats = (float2*)((char*)d_out + (9u << 20));

    dim3 blk(256);
    maskpack_kernel<<<dim3((B_ * T_ * T_) / 256), blk, 0, stream>>>(mask, bits);
    splitx_kernel<<<dim3((B_ * T_ * D_) / 2048), blk, 0, stream>>>(X, Xhi, Xlo);
    wtr_kernel<<<dim3(16, 16, 4), blk, 0, stream>>>(
        Wq, Wk, Wv, Wo, WqThi, WqTlo, WkThi, WkTlo, WvT, WoT);
    gemm_kernel<<<dim3(D_ / 128, (B_ * T_) / 128, 3), blk, 0, stream>>>(
        Xhi, Xlo, 0, WqThi, WqTlo, WkThi, WkTlo, WvT, WoT,
        bq, bk, bv, bo, Qhi, Qlo, Khi, Klo, Vt, out);
    attn_split_kernel<<<dim3(B_ * H_ * (T_ / 128) * NSPLIT), blk, 0, stream>>>(
        Qhi, Qlo, Khi, Klo, Vt, bits, Op0, Op1, stats);
    combine_kernel<<<dim3((32 * T_) / 32), blk, 0, stream>>>(
        Op0, Op1, stats, comb);
    gemm_kernel<<<dim3(D_ / 128, (B_ * T_) / 128, 1), blk, 0, stream>>>(
        comb, nullptr, 3, WqThi, WqTlo, WkThi, WkTlo, WvT, WoT,
        bq, bk, bv, bo, Qhi, Qlo, Khi, Klo, Vt, out);
}

// Round 6
// 307.763 us; speedup vs baseline: 1.9022x; 1.9022x over previous
//
#include <hip/hip_runtime.h>
#include <hip/hip_bf16.h>
#include <stdint.h>

typedef __attribute__((ext_vector_type(8))) short short8;
typedef __attribute__((ext_vector_type(4))) float f32x4;
typedef __attribute__((ext_vector_type(16))) float f32x16;
typedef unsigned short u16;

#define B_  2
#define T_  2048
#define D_  1024
#define H_  16
#define DH_ 64
#define NSPLIT 2
#define KVSPAN (T_ / NSPLIT)

__device__ __forceinline__ u16 f2bf(float x) {
    union { float f; uint32_t u; } v; v.f = x;
    uint32_t r = v.u + 0x7fffu + ((v.u >> 16) & 1u);
    return (u16)(r >> 16);
}
__device__ __forceinline__ float bf2f(u16 h) {
    union { uint32_t u; float f; } v; v.u = ((uint32_t)h) << 16;
    return v.f;
}
__device__ __forceinline__ f32x4 mfma16(short8 a, short8 b, f32x4 c) {
    return __builtin_amdgcn_mfma_f32_16x16x32_bf16(a, b, c, 0, 0, 0);
}
__device__ __forceinline__ f32x16 mfma32(short8 a, short8 b, f32x16 c) {
    return __builtin_amdgcn_mfma_f32_32x32x16_bf16(a, b, c, 0, 0, 0);
}
__device__ __forceinline__ void gload16(const u16* g, u16* l) {
    __builtin_amdgcn_global_load_lds(
        (const __attribute__((address_space(1))) uint32_t*)g,
        (__attribute__((address_space(3))) uint32_t*)l, 16, 0, 0);
}

// ---------------------------------------------------------------------------
// Kernel 0: pack int32 mask -> bit mask (1 MB, L2-resident in attn).
// ---------------------------------------------------------------------------
__global__ __launch_bounds__(256) void maskpack_kernel(
    const int* __restrict__ mask, uint32_t* __restrict__ bits)
{
    size_t e = (size_t)blockIdx.x * 256 + threadIdx.x;
    unsigned long long b = __ballot(mask[e] != 0);
    if ((threadIdx.x & 63) == 0)
        *(unsigned long long*)(bits + (e >> 5)) = b;
}

// ---------------------------------------------------------------------------
// Kernel 0b: split X fp32 -> Xhi/Xlo bf16 (one-time conversion).
// ---------------------------------------------------------------------------
__global__ __launch_bounds__(256) void splitx_kernel(
    const float* __restrict__ X, u16* __restrict__ Xhi, u16* __restrict__ Xlo)
{
    size_t i0 = ((size_t)blockIdx.x * 256 + threadIdx.x) * 8;
    float4 a = *(const float4*)(X + i0);
    float4 b = *(const float4*)(X + i0 + 4);
    float v[8] = {a.x, a.y, a.z, a.w, b.x, b.y, b.z, b.w};
    union { u16 h[8]; short8 s; } Hh, Ll;
#pragma unroll
    for (int i = 0; i < 8; ++i) {
        Hh.h[i] = f2bf(v[i]);
        Ll.h[i] = f2bf(v[i] - bf2f(Hh.h[i]));
    }
    *(short8*)(Xhi + i0) = Hh.s;
    *(short8*)(Xlo + i0) = Ll.s;
}

// ---------------------------------------------------------------------------
// Kernel 0c: transpose + split weights.  W[k][n] fp32 -> WT[n][k] bf16.
// ---------------------------------------------------------------------------
__global__ __launch_bounds__(256) void wtr_kernel(
    const float* __restrict__ Wq, const float* __restrict__ Wk,
    const float* __restrict__ Wv, const float* __restrict__ Wo,
    u16* __restrict__ WqThi, u16* __restrict__ WqTlo,
    u16* __restrict__ WkThi, u16* __restrict__ WkTlo,
    u16* __restrict__ WvT,   u16* __restrict__ WoT)
{
    __shared__ float s_t[64][65];
    const int zz = blockIdx.z;
    const float* __restrict__ W = (zz == 0) ? Wq : (zz == 1) ? Wk : (zz == 2) ? Wv : Wo;
    const int k0 = blockIdx.y * 64, n0 = blockIdx.x * 64;
    const int t = threadIdx.x;
    const int r = t >> 2, c0 = (t & 3) * 16;

#pragma unroll
    for (int j = 0; j < 4; ++j) {
        float4 v = *(const float4*)(W + (size_t)(k0 + r) * D_ + n0 + c0 + j * 4);
        s_t[r][c0 + j * 4 + 0] = v.x;
        s_t[r][c0 + j * 4 + 1] = v.y;
        s_t[r][c0 + j * 4 + 2] = v.z;
        s_t[r][c0 + j * 4 + 3] = v.w;
    }
    __syncthreads();

    const int n = t >> 2, kc = (t & 3) * 16;
    union { u16 h[16]; short8 s[2]; } Hh, Ll;
#pragma unroll
    for (int j = 0; j < 16; ++j) {
        float x = s_t[kc + j][n];
        Hh.h[j] = f2bf(x);
        Ll.h[j] = f2bf(x - bf2f(Hh.h[j]));
    }
    u16* dh = (zz == 0) ? WqThi : (zz == 1) ? WkThi : (zz == 2) ? WvT : WoT;
    u16* dl = (zz == 0) ? WqTlo : (zz == 1) ? WkTlo : nullptr;
    size_t o = (size_t)(n0 + n) * D_ + k0 + kc;
    *(short8*)(dh + o) = Hh.s[0];
    *(short8*)(dh + o + 8) = Hh.s[1];
    if (dl) {
        *(short8*)(dl + o) = Ll.s[0];
        *(short8*)(dl + o + 8) = Ll.s[1];
    }
}

// ---------------------------------------------------------------------------
// Kernel 1: m97-style 128x128 GEMM, BK=32, global_load_lds staging.
// z: 0=Q (split out, *1/8)  1=K (split out)  2=V (bf16, [B,H,64,T])  3=O (fp32)
// ---------------------------------------------------------------------------
__global__ __launch_bounds__(256) void gemm_kernel(
    const u16* __restrict__ Ahi, const u16* __restrict__ Alo, int zbase,
    const u16* __restrict__ BqH, const u16* __restrict__ BqL,
    const u16* __restrict__ BkH, const u16* __restrict__ BkL,
    const u16* __restrict__ BvT, const u16* __restrict__ BoT,
    const float* __restrict__ bq, const float* __restrict__ bk,
    const float* __restrict__ bv, const float* __restrict__ bo,
    u16* __restrict__ Qhi, u16* __restrict__ Qlo,
    u16* __restrict__ Khi, u16* __restrict__ Klo,
    u16* __restrict__ Vt,  float* __restrict__ outF)
{
    __shared__ u16 sAhi[128 * 32];
    __shared__ u16 sAlo[128 * 32];
    __shared__ u16 sBhi[128 * 32];
    __shared__ u16 sBlo[128 * 32];

    const int z = blockIdx.z + zbase;
    const u16* __restrict__ Bh = (z == 0) ? BqH : (z == 1) ? BkH : (z == 2) ? BvT : BoT;
    const u16* __restrict__ Bl = (z == 0) ? BqL : (z == 1) ? BkL : nullptr;
    const float* __restrict__ bias = (z == 0) ? bq : (z == 1) ? bk : (z == 2) ? bv : bo;
    const bool split = (z < 2);

    const int m0 = blockIdx.y * 128;
    const int n0 = blockIdx.x * 128;
    const int tid = threadIdx.x;
    const int w = tid >> 6, l = tid & 63;
    const int g = l >> 4, lr = l & 15;
    const int wm = w >> 1, wn = w & 1;

    const int srow = w * 32 + (l >> 2);
    const int skb  = (l & 3) * 8;

    f32x4 acc[4][4] = {};

    for (int k0 = 0; k0 < D_; k0 += 32) {
        __syncthreads();
#pragma unroll
        for (int i = 0; i < 2; ++i) {
            gload16(Ahi + (size_t)(m0 + srow + i * 16) * D_ + k0 + skb,
                    &sAhi[w * 1024 + i * 512]);
            gload16(Bh + (size_t)(n0 + srow + i * 16) * D_ + k0 + skb,
                    &sBhi[w * 1024 + i * 512]);
        }
        if (split) {
#pragma unroll
            for (int i = 0; i < 2; ++i) {
                gload16(Alo + (size_t)(m0 + srow + i * 16) * D_ + k0 + skb,
                        &sAlo[w * 1024 + i * 512]);
                gload16(Bl + (size_t)(n0 + srow + i * 16) * D_ + k0 + skb,
                        &sBlo[w * 1024 + i * 512]);
            }
        }
        __syncthreads();

        short8 ah[4], bh[4];
#pragma unroll
        for (int f = 0; f < 4; ++f) {
            ah[f] = *(const short8*)&sAhi[(wm * 64 + f * 16 + lr) * 32 + g * 8];
            bh[f] = *(const short8*)&sBhi[(wn * 64 + f * 16 + lr) * 32 + g * 8];
        }
#pragma unroll
        for (int fm = 0; fm < 4; ++fm)
#pragma unroll
            for (int fn = 0; fn < 4; ++fn)
                acc[fm][fn] = mfma16(ah[fm], bh[fn], acc[fm][fn]);
        if (split) {
            short8 al[4], bl[4];
#pragma unroll
            for (int f = 0; f < 4; ++f) {
                al[f] = *(const short8*)&sAlo[(wm * 64 + f * 16 + lr) * 32 + g * 8];
                bl[f] = *(const short8*)&sBlo[(wn * 64 + f * 16 + lr) * 32 + g * 8];
            }
#pragma unroll
            for (int fm = 0; fm < 4; ++fm)
#pragma unroll
                for (int fn = 0; fn < 4; ++fn) {
                    acc[fm][fn] = mfma16(ah[fm], bl[fn], acc[fm][fn]);
                    acc[fm][fn] = mfma16(al[fm], bh[fn], acc[fm][fn]);
                }
        }
    }

    const float scale = (z == 0) ? 0.125f : 1.0f;
    float biasv[4];
#pragma unroll
    for (int f = 0; f < 4; ++f) biasv[f] = bias[n0 + wn * 64 + f * 16 + lr];

    if (z <= 1) {
        u16* Oh = (z == 0) ? Qhi : Khi;
        u16* Ol = (z == 0) ? Qlo : Klo;
#pragma unroll
        for (int fm = 0; fm < 4; ++fm)
#pragma unroll
            for (int fn = 0; fn < 4; ++fn)
#pragma unroll
                for (int j = 0; j < 4; ++j) {
                    int r = m0 + wm * 64 + fm * 16 + g * 4 + j;
                    int c = n0 + wn * 64 + fn * 16 + lr;
                    float v = (acc[fm][fn][j] + biasv[fn]) * scale;
                    int b = r >> 11, t = r & (T_ - 1);
                    int h = (c >> 6) & 15, d = c & 63;
                    size_t idx = ((size_t)(b * H_ + h) * T_ + t) * DH_ + d;
                    u16 hv = f2bf(v);
                    Oh[idx] = hv;
                    Ol[idx] = f2bf(v - bf2f(hv));
                }
    } else if (z == 2) {
#pragma unroll
        for (int fm = 0; fm < 4; ++fm)
#pragma unroll
            for (int fn = 0; fn < 4; ++fn) {
                int r0 = m0 + wm * 64 + fm * 16 + g * 4;
                int c  = n0 + wn * 64 + fn * 16 + lr;
                int b = r0 >> 11, t0 = r0 & (T_ - 1);
                int h = (c >> 6) & 15, d = c & 63;
                uint2 pk;
                pk.x = (uint32_t)f2bf(acc[fm][fn][0] + biasv[fn]) |
                       ((uint32_t)f2bf(acc[fm][fn][1] + biasv[fn]) << 16);
                pk.y = (uint32_t)f2bf(acc[fm][fn][2] + biasv[fn]) |
                       ((uint32_t)f2bf(acc[fm][fn][3] + biasv[fn]) << 16);
                *(uint2*)&Vt[((size_t)(b * H_ + h) * DH_ + d) * T_ + t0] = pk;
            }
    } else {
#pragma unroll
        for (int fm = 0; fm < 4; ++fm)
#pragma unroll
            for (int fn = 0; fn < 4; ++fn)
#pragma unroll
                for (int j = 0; j < 4; ++j) {
                    int r = m0 + wm * 64 + fm * 16 + g * 4 + j;
                    int c = n0 + wn * 64 + fn * 16 + lr;
                    outF[(size_t)r * D_ + c] = acc[fm][fn][j] + biasv[fn];
                }
    }
}

// ---------------------------------------------------------------------------
// Kernel 2: flash attention, swapped-QK^T 32x32x16, KV-SPLIT x2 across blocks
// (grid 1024; VGPR ~108 -> 4 waves/SIMD naturally), register double-buffer,
// tree reductions, XCD swizzle.  NOTE: launch_bounds min-waves stays at 2 —
// forcing 4 caps unified VGPR at 128 and spills to scratch (R5: 2 GB traffic).
// ---------------------------------------------------------------------------
__device__ __forceinline__ void attn_tile(
    const short8* kh, const short8* kl, const short8* vb, uint32_t mw,
    const short8* qfh, const short8* qfl,
    f32x16& o0, f32x16& o1, float& m_run, float& l_run)
{
    const float L2E = 1.4426950408889634f;
    f32x16 s = {};
    __builtin_amdgcn_s_setprio(1);
#pragma unroll
    for (int c = 0; c < 4; ++c) {
        s = mfma32(kh[c], qfh[c], s);
        s = mfma32(kh[c], qfl[c], s);
        s = mfma32(kl[c], qfh[c], s);
    }
    __builtin_amdgcn_s_setprio(0);

#pragma unroll
    for (int r = 0; r < 16; ++r) {
        const int bit = (r & 3) + 8 * (r >> 2);
        if (!((mw >> bit) & 1u)) s[r] = -1e30f;
    }

    // tree row-max (depth 4 + cross-half)
    float t8[8], t4[4], t2[2];
#pragma unroll
    for (int i = 0; i < 8; ++i) t8[i] = fmaxf(s[i], s[i + 8]);
#pragma unroll
    for (int i = 0; i < 4; ++i) t4[i] = fmaxf(t8[i], t8[i + 4]);
    t2[0] = fmaxf(t4[0], t4[2]); t2[1] = fmaxf(t4[1], t4[3]);
    float pm = fmaxf(t2[0], t2[1]);
    pm = fmaxf(pm, __shfl_xor(pm, 32));

    if (__any(pm > m_run + 8.0f)) {        // defer-max rescale (T13)
        float mn  = fmaxf(m_run, pm);
        float fac = exp2f((m_run - mn) * L2E);
        l_run *= fac;
#pragma unroll
        for (int r = 0; r < 16; ++r) { o0[r] *= fac; o1[r] *= fac; }
        m_run = mn;
    }

    float p[16];
#pragma unroll
    for (int r = 0; r < 16; ++r) p[r] = exp2f((s[r] - m_run) * L2E);
    // tree row-sum
    float a8[8], a4[4], a2[2];
#pragma unroll
    for (int i = 0; i < 8; ++i) a8[i] = p[i] + p[i + 8];
#pragma unroll
    for (int i = 0; i < 4; ++i) a4[i] = a8[i] + a8[i + 4];
    a2[0] = a4[0] + a4[2]; a2[1] = a4[1] + a4[3];
    float sum = a2[0] + a2[1];
    sum += __shfl_xor(sum, 32);
    l_run += sum;

    uint32_t wv[8];
#pragma unroll
    for (int m2 = 0; m2 < 8; ++m2)
        asm("v_cvt_pk_bf16_f32 %0, %1, %2"
            : "=v"(wv[m2]) : "v"(p[2 * m2]), "v"(p[2 * m2 + 1]));
    asm("v_permlane32_swap_b32 %0, %1" : "+v"(wv[0]), "+v"(wv[2]));
    asm("v_permlane32_swap_b32 %0, %1" : "+v"(wv[1]), "+v"(wv[3]));
    asm("v_permlane32_swap_b32 %0, %1" : "+v"(wv[4]), "+v"(wv[6]));
    asm("v_permlane32_swap_b32 %0, %1" : "+v"(wv[5]), "+v"(wv[7]));
    union { uint32_t u[4]; short8 s8; } pa1, pa2;
    pa1.u[0] = wv[0]; pa1.u[1] = wv[1]; pa1.u[2] = wv[2]; pa1.u[3] = wv[3];
    pa2.u[0] = wv[4]; pa2.u[1] = wv[5]; pa2.u[2] = wv[6]; pa2.u[3] = wv[7];

    __builtin_amdgcn_s_setprio(1);
    o0 = mfma32(vb[0], pa1.s8, o0);
    o0 = mfma32(vb[1], pa2.s8, o0);
    o1 = mfma32(vb[2], pa1.s8, o1);
    o1 = mfma32(vb[3], pa2.s8, o1);
    __builtin_amdgcn_s_setprio(0);
}

#define LOAD_TILE(kh, kl, vb, mw, kv)                                          \
    do {                                                                       \
        _Pragma("unroll")                                                      \
        for (int c = 0; c < 4; ++c) {                                          \
            kh[c] = *(const short8*)&Kh[(size_t)((kv) + qi) * DH_ + c * 16 + hl * 8]; \
            kl[c] = *(const short8*)&Kl[(size_t)((kv) + qi) * DH_ + c * 16 + hl * 8]; \
        }                                                                      \
        vb[0] = *(const short8*)&Vh[(size_t)(qi) * T_ + (kv) + hl * 8];        \
        vb[1] = *(const short8*)&Vh[(size_t)(qi) * T_ + (kv) + 16 + hl * 8];   \
        vb[2] = *(const short8*)&Vh[(size_t)(32 + qi) * T_ + (kv) + hl * 8];   \
        vb[3] = *(const short8*)&Vh[(size_t)(32 + qi) * T_ + (kv) + 16 + hl * 8]; \
        mw = mrow[(kv) >> 5] >> (hl * 4);                                      \
    } while (0)

__global__ __launch_bounds__(256, 2) void attn_split_kernel(
    const u16* __restrict__ Qhi, const u16* __restrict__ Qlo,
    const u16* __restrict__ Khi, const u16* __restrict__ Klo,
    const u16* __restrict__ Vt,  const uint32_t* __restrict__ bits,
    u16* __restrict__ Op0, u16* __restrict__ Op1,
    float2* __restrict__ stats)
{
    // bx = (hi<<8)|(mid<<3)|lo ; bh = lo|(hi<<3) -> all 32 (qb,sp) blocks of
    // one bh share bx%8 => same XCD under round-robin dispatch.
    const int bx  = blockIdx.x;
    const int bh  = (bx & 7) | ((bx >> 8) << 3);
    const int mid = (bx >> 3) & 31;
    const int qb  = mid >> 1;
    const int sp  = mid & 1;
    const int b   = bh >> 4, h = bh & 15;
    const int tid = threadIdx.x;
    const int w   = tid >> 6;
    const int l   = tid & 63;
    const int qi  = l & 31;
    const int hl  = l >> 5;
    const int q   = qb * 128 + w * 32 + qi;
    const int kvbase = sp * KVSPAN;

    const size_t hoff = (size_t)(b * H_ + h) * T_ * DH_;
    const u16* Qh = Qhi + hoff;
    const u16* Ql = Qlo + hoff;
    const u16* Kh = Khi + hoff;
    const u16* Kl = Klo + hoff;
    const u16* Vh = Vt  + hoff;                        // [64][T]
    const uint32_t* mrow = bits + ((size_t)b * T_ + q) * (T_ / 32);

    short8 qfh[4], qfl[4];
#pragma unroll
    for (int c = 0; c < 4; ++c) {
        qfh[c] = *(const short8*)&Qh[(size_t)q * DH_ + c * 16 + hl * 8];
        qfl[c] = *(const short8*)&Ql[(size_t)q * DH_ + c * 16 + hl * 8];
    }

    f32x16 o0 = {}; f32x16 o1 = {};
    float m_run = -1e30f, l_run = 0.0f;

    short8 khA[4], klA[4], vbA[4]; uint32_t mwA;
    short8 khB[4], klB[4], vbB[4]; uint32_t mwB;

    LOAD_TILE(khA, klA, vbA, mwA, kvbase);

    for (int kv0 = kvbase; kv0 < kvbase + KVSPAN; kv0 += 64) {
        LOAD_TILE(khB, klB, vbB, mwB, kv0 + 32);
        attn_tile(khA, klA, vbA, mwA, qfh, qfl, o0, o1, m_run, l_run);
        LOAD_TILE(khA, klA, vbA, mwA,
                  kvbase + ((kv0 + 64 - kvbase) & (KVSPAN - 1)));  // wraps
        attn_tile(khB, klB, vbB, mwB, qfh, qfl, o0, o1, m_run, l_run);
    }

    // epilogue: normalized partial O -> Op[sp], stats (m,l) -> stats[sp]
    float inv = 1.0f / l_run;
    float ov[32];
#pragma unroll
    for (int r = 0; r < 16; ++r) { ov[r] = o0[r]; ov[16 + r] = o1[r]; }
    u16* Op = (sp == 0) ? Op0 : Op1;
    u16* prow = Op + ((size_t)bh * T_ + q) * DH_;
#pragma unroll
    for (int dt = 0; dt < 2; ++dt)
#pragma unroll
        for (int g2 = 0; g2 < 4; ++g2) {
            float v0 = ov[dt * 16 + 4 * g2 + 0] * inv;
            float v1 = ov[dt * 16 + 4 * g2 + 1] * inv;
            float v2 = ov[dt * 16 + 4 * g2 + 2] * inv;
            float v3 = ov[dt * 16 + 4 * g2 + 3] * inv;
            uint2 pkt;
            pkt.x = (uint32_t)f2bf(v0) | ((uint32_t)f2bf(v1) << 16);
            pkt.y = (uint32_t)f2bf(v2) | ((uint32_t)f2bf(v3) << 16);
            *(uint2*)(prow + dt * 32 + 8 * g2 + 4 * hl) = pkt;
        }
    if (hl == 0)
        stats[(size_t)sp * (32 * T_) + (size_t)bh * T_ + q] =
            make_float2(m_run, l_run);
}

// ---------------------------------------------------------------------------
// Kernel 2b: combine the two KV-split partials -> comb (bf16 [B,T,D]).
// O = (w0*O0 + w1*O1)/(w0+w1), w_i = l_i * exp2((m_i - m)*log2e).
// ---------------------------------------------------------------------------
__global__ __launch_bounds__(256) void combine_kernel(
    const u16* __restrict__ Op0, const u16* __restrict__ Op1,
    const float2* __restrict__ stats, u16* __restrict__ comb)
{
    const float L2E = 1.4426950408889634f;
    const int row = blockIdx.x * 32 + (threadIdx.x >> 3);   // [0, 32*T_)
    const int dh0 = (threadIdx.x & 7) * 8;
    const int bh = row >> 11, q = row & (T_ - 1);
    const int b = bh >> 4, h = bh & 15;

    float2 s0 = stats[row];
    float2 s1 = stats[32 * T_ + row];
    float m = fmaxf(s0.x, s1.x);
    float w0 = s0.y * exp2f((s0.x - m) * L2E);
    float w1 = s1.y * exp2f((s1.x - m) * L2E);
    float rs = 1.0f / (w0 + w1);
    float a0 = w0 * rs, a1 = w1 * rs;

    union { short8 s; u16 h[8]; } v0, v1, ou;
    v0.s = *(const short8*)(Op0 + (size_t)row * DH_ + dh0);
    v1.s = *(const short8*)(Op1 + (size_t)row * DH_ + dh0);
#pragma unroll
    for (int i = 0; i < 8; ++i)
        ou.h[i] = f2bf(a0 * bf2f(v0.h[i]) + a1 * bf2f(v1.h[i]));
    *(short8*)(comb + ((size_t)(b * T_ + q)) * D_ + h * DH_ + dh0) = ou.s;
}

// ---------------------------------------------------------------------------
extern "C" void kernel_launch(void* const* d_in, const int* in_sizes, int n_in,
                              void* d_out, int out_size, void* d_ws, size_t ws_size,
                              hipStream_t stream)
{
    const float* X    = (const float*)d_in[0];
    const int*   mask = (const int*)d_in[1];
    const float* Wq   = (const float*)d_in[2];
    const float* bq   = (const float*)d_in[3];
    const float* Wk   = (const float*)d_in[4];
    const float* bk   = (const float*)d_in[5];
    const float* Wv   = (const float*)d_in[6];
    const float* bv   = (const float*)d_in[7];
    const float* Wo   = (const float*)d_in[8];
    const float* bo   = (const float*)d_in[9];
    float* out = (float*)d_out;

    const size_t SEG = (size_t)B_ * H_ * T_ * DH_;   // = B*T*D elems
    const size_t WSEG = (size_t)D_ * D_;
    u16* wsp = (u16*)d_ws;
    u16* Qhi   = wsp + 0 * SEG;
    u16* Qlo   = wsp + 1 * SEG;
    u16* Khi   = wsp + 2 * SEG;
    u16* Klo   = wsp + 3 * SEG;
    u16* Xhi   = wsp + 4 * SEG;        // comb aliases Xhi after QKV GEMM
    u16* Xlo   = wsp + 5 * SEG;        // Op0 aliases Xlo after QKV GEMM
    u16* WqThi = wsp + 6 * SEG;        // Op1 aliases WqT/WkT after QKV GEMM
    u16* WqTlo = WqThi + WSEG;
    u16* WkThi = WqThi + 2 * WSEG;
    u16* WkTlo = WqThi + 3 * WSEG;
    u16* WvT   = WqThi + 4 * WSEG;
    u16* WoT   = WqThi + 5 * WSEG;
    u16* comb  = Xhi;
    u16* Op0   = Xlo;
    u16* Op1   = WqThi;
    // d_out scratch: Vt (8 MiB) + bits (1 MiB) + stats (1 MiB); final GEMM
    // overwrites all of d_out.
    u16* Vt = (u16*)d_out;
    uint32_t* bits = (uint32_t*)((char*)d_out + (8u << 20));
    float2* stats = (float2*)((char*)d_out + (9u << 20));

    dim3 blk(256);
    maskpack_kernel<<<dim3((B_ * T_ * T_) / 256), blk, 0, stream>>>(mask, bits);
    splitx_kernel<<<dim3((B_ * T_ * D_) / 2048), blk, 0, stream>>>(X, Xhi, Xlo);
    wtr_kernel<<<dim3(16, 16, 4), blk, 0, stream>>>(
        Wq, Wk, Wv, Wo, WqThi, WqTlo, WkThi, WkTlo, WvT, WoT);
    gemm_kernel<<<dim3(D_ / 128, (B_ * T_) / 128, 3), blk, 0, stream>>>(
        Xhi, Xlo, 0, WqThi, WqTlo, WkThi, WkTlo, WvT, WoT,
        bq, bk, bv, bo, Qhi, Qlo, Khi, Klo, Vt, out);
    attn_split_kernel<<<dim3(B_ * H_ * (T_ / 128) * NSPLIT), blk, 0, stream>>>(
        Qhi, Qlo, Khi, Klo, Vt, bits, Op0, Op1, stats);
    combine_kernel<<<dim3((32 * T_) / 32), blk, 0, stream>>>(
        Op0, Op1, stats, comb);
    gemm_kernel<<<dim3(D_ / 128, (B_ * T_) / 128, 1), blk, 0, stream>>>(
        comb, nullptr, 3, WqThi, WqTlo, WkThi, WkTlo, WvT, WoT,
        bq, bk, bv, bo, Qhi, Qlo, Khi, Klo, Vt, out);
}

// Round 9
// 240.023 us; speedup vs baseline: 2.4390x; 1.2822x over previous
//
#include <hip/hip_runtime.h>
#include <hip/hip_bf16.h>
#include <stdint.h>

typedef _Float16 f16;
typedef __attribute__((ext_vector_type(8))) _Float16 f16x8;
typedef __attribute__((ext_vector_type(2))) __fp16 fp16x2;
typedef __attribute__((ext_vector_type(4))) float f32x4;
typedef __attribute__((ext_vector_type(16))) float f32x16;

#define B_  2
#define T_  2048
#define D_  1024
#define H_  16
#define DH_ 64
#define NSPLIT 2
#define KVSPAN (T_ / NSPLIT)

__device__ __forceinline__ f32x4 mfma16f(f16x8 a, f16x8 b, f32x4 c) {
    return __builtin_amdgcn_mfma_f32_16x16x32_f16(a, b, c, 0, 0, 0);
}
__device__ __forceinline__ f32x16 mfma32f(f16x8 a, f16x8 b, f32x16 c) {
    return __builtin_amdgcn_mfma_f32_32x32x16_f16(a, b, c, 0, 0, 0);
}
__device__ __forceinline__ void gload16(const void* g, void* l) {
    __builtin_amdgcn_global_load_lds(
        (const __attribute__((address_space(1))) uint32_t*)g,
        (__attribute__((address_space(3))) uint32_t*)l, 16, 0, 0);
}

// ---------------------------------------------------------------------------
// Kernel 0: pack int32 mask -> bit mask (1 MB, L2-resident in attn).
// ---------------------------------------------------------------------------
__global__ __launch_bounds__(256) void maskpack_kernel(
    const int* __restrict__ mask, uint32_t* __restrict__ bits)
{
    size_t e = (size_t)blockIdx.x * 256 + threadIdx.x;
    unsigned long long b = __ballot(mask[e] != 0);
    if ((threadIdx.x & 63) == 0)
        *(unsigned long long*)(bits + (e >> 5)) = b;
}

// ---------------------------------------------------------------------------
// Kernel 0b: split X fp32 -> Xh/Xl fp16 (2-term split: eff. ~22-bit mantissa).
// ---------------------------------------------------------------------------
__global__ __launch_bounds__(256) void splitx_kernel(
    const float* __restrict__ X, f16* __restrict__ Xh, f16* __restrict__ Xl)
{
    size_t i0 = ((size_t)blockIdx.x * 256 + threadIdx.x) * 8;
    float4 a = *(const float4*)(X + i0);
    float4 b = *(const float4*)(X + i0 + 4);
    float v[8] = {a.x, a.y, a.z, a.w, b.x, b.y, b.z, b.w};
    f16x8 hh, ll;
#pragma unroll
    for (int i = 0; i < 8; ++i) {
        f16 h = (f16)v[i];
        hh[i] = h;
        ll[i] = (f16)(v[i] - (float)h);
    }
    *(f16x8*)(Xh + i0) = hh;
    *(f16x8*)(Xl + i0) = ll;
}

// ---------------------------------------------------------------------------
// Kernel 0c: transpose weights.  W[k][n] fp32 -> WT[n][k] fp16 (single).
// ---------------------------------------------------------------------------
__global__ __launch_bounds__(256) void wtr_kernel(
    const float* __restrict__ Wq, const float* __restrict__ Wk,
    const float* __restrict__ Wv, const float* __restrict__ Wo,
    f16* __restrict__ WqT, f16* __restrict__ WkT,
    f16* __restrict__ WvT, f16* __restrict__ WoT)
{
    __shared__ float s_t[64][65];
    const int zz = blockIdx.z;
    const float* __restrict__ W = (zz == 0) ? Wq : (zz == 1) ? Wk : (zz == 2) ? Wv : Wo;
    const int k0 = blockIdx.y * 64, n0 = blockIdx.x * 64;
    const int t = threadIdx.x;
    const int r = t >> 2, c0 = (t & 3) * 16;

#pragma unroll
    for (int j = 0; j < 4; ++j) {
        float4 v = *(const float4*)(W + (size_t)(k0 + r) * D_ + n0 + c0 + j * 4);
        s_t[r][c0 + j * 4 + 0] = v.x;
        s_t[r][c0 + j * 4 + 1] = v.y;
        s_t[r][c0 + j * 4 + 2] = v.z;
        s_t[r][c0 + j * 4 + 3] = v.w;
    }
    __syncthreads();

    const int n = t >> 2, kc = (t & 3) * 16;
    f16x8 h0, h1;
#pragma unroll
    for (int j = 0; j < 8; ++j) h0[j] = (f16)s_t[kc + j][n];
#pragma unroll
    for (int j = 0; j < 8; ++j) h1[j] = (f16)s_t[kc + 8 + j][n];
    f16* dh = (zz == 0) ? WqT : (zz == 1) ? WkT : (zz == 2) ? WvT : WoT;
    size_t o = (size_t)(n0 + n) * D_ + k0 + kc;
    *(f16x8*)(dh + o) = h0;
    *(f16x8*)(dh + o + 8) = h1;
}

// ---------------------------------------------------------------------------
// Kernel 1: 128x128 fp16 GEMM, BK=32, global_load_lds staging.
// z: 0=Q (fp16 out, *1/8; 2-term A-split)  1=K (fp16 out; 2-term)
//    2=V (fp16 out, transposed [B,H,64,T]; 1-term)  3=O (fp32 out; 1-term)
// ---------------------------------------------------------------------------
__global__ __launch_bounds__(256) void gemm_kernel(
    const f16* __restrict__ Ahi, const f16* __restrict__ Alo, int zbase,
    const f16* __restrict__ BqT, const f16* __restrict__ BkT,
    const f16* __restrict__ BvT, const f16* __restrict__ BoT,
    const float* __restrict__ bq, const float* __restrict__ bk,
    const float* __restrict__ bv, const float* __restrict__ bo,
    f16* __restrict__ Q, f16* __restrict__ K,
    f16* __restrict__ Vt, float* __restrict__ outF)
{
    __shared__ f16 sAh[128 * 32];
    __shared__ f16 sAl[128 * 32];
    __shared__ f16 sB [128 * 32];

    const int z = blockIdx.z + zbase;
    const f16* __restrict__ Bm = (z == 0) ? BqT : (z == 1) ? BkT : (z == 2) ? BvT : BoT;
    const float* __restrict__ bias = (z == 0) ? bq : (z == 1) ? bk : (z == 2) ? bv : bo;
    const bool split = (z < 2);

    const int m0 = blockIdx.y * 128;
    const int n0 = blockIdx.x * 128;
    const int tid = threadIdx.x;
    const int w = tid >> 6, l = tid & 63;
    const int g = l >> 4, lr = l & 15;
    const int wm = w >> 1, wn = w & 1;

    const int srow = w * 32 + (l >> 2);
    const int skb  = (l & 3) * 8;

    f32x4 acc[4][4] = {};

    for (int k0 = 0; k0 < D_; k0 += 32) {
        __syncthreads();
#pragma unroll
        for (int i = 0; i < 2; ++i) {
            gload16(Ahi + (size_t)(m0 + srow + i * 16) * D_ + k0 + skb,
                    &sAh[w * 1024 + i * 512]);
            gload16(Bm + (size_t)(n0 + srow + i * 16) * D_ + k0 + skb,
                    &sB[w * 1024 + i * 512]);
        }
        if (split) {
#pragma unroll
            for (int i = 0; i < 2; ++i)
                gload16(Alo + (size_t)(m0 + srow + i * 16) * D_ + k0 + skb,
                        &sAl[w * 1024 + i * 512]);
        }
        __syncthreads();

        f16x8 ah[4], bh[4];
#pragma unroll
        for (int f = 0; f < 4; ++f) {
            ah[f] = *(const f16x8*)&sAh[(wm * 64 + f * 16 + lr) * 32 + g * 8];
            bh[f] = *(const f16x8*)&sB [(wn * 64 + f * 16 + lr) * 32 + g * 8];
        }
#pragma unroll
        for (int fm = 0; fm < 4; ++fm)
#pragma unroll
            for (int fn = 0; fn < 4; ++fn)
                acc[fm][fn] = mfma16f(ah[fm], bh[fn], acc[fm][fn]);
        if (split) {
            f16x8 al[4];
#pragma unroll
            for (int f = 0; f < 4; ++f)
                al[f] = *(const f16x8*)&sAl[(wm * 64 + f * 16 + lr) * 32 + g * 8];
#pragma unroll
            for (int fm = 0; fm < 4; ++fm)
#pragma unroll
                for (int fn = 0; fn < 4; ++fn)
                    acc[fm][fn] = mfma16f(al[fm], bh[fn], acc[fm][fn]);
        }
    }

    const float scale = (z == 0) ? 0.125f : 1.0f;
    float biasv[4];
#pragma unroll
    for (int f = 0; f < 4; ++f) biasv[f] = bias[n0 + wn * 64 + f * 16 + lr];

    if (z <= 1) {
        f16* Oq = (z == 0) ? Q : K;
#pragma unroll
        for (int fm = 0; fm < 4; ++fm)
#pragma unroll
            for (int fn = 0; fn < 4; ++fn)
#pragma unroll
                for (int j = 0; j < 4; ++j) {
                    int r = m0 + wm * 64 + fm * 16 + g * 4 + j;
                    int c = n0 + wn * 64 + fn * 16 + lr;
                    float v = (acc[fm][fn][j] + biasv[fn]) * scale;
                    int b = r >> 11, t = r & (T_ - 1);
                    int h = (c >> 6) & 15, d = c & 63;
                    Oq[((size_t)(b * H_ + h) * T_ + t) * DH_ + d] = (f16)v;
                }
    } else if (z == 2) {
#pragma unroll
        for (int fm = 0; fm < 4; ++fm)
#pragma unroll
            for (int fn = 0; fn < 4; ++fn) {
                int r0 = m0 + wm * 64 + fm * 16 + g * 4;
                int c  = n0 + wn * 64 + fn * 16 + lr;
                int b = r0 >> 11, t0 = r0 & (T_ - 1);
                int h = (c >> 6) & 15, d = c & 63;
                union { f16 h4[4]; uint2 u; } pk;
#pragma unroll
                for (int j = 0; j < 4; ++j)
                    pk.h4[j] = (f16)(acc[fm][fn][j] + biasv[fn]);
                *(uint2*)&Vt[((size_t)(b * H_ + h) * DH_ + d) * T_ + t0] = pk.u;
            }
    } else {
#pragma unroll
        for (int fm = 0; fm < 4; ++fm)
#pragma unroll
            for (int fn = 0; fn < 4; ++fn)
#pragma unroll
                for (int j = 0; j < 4; ++j) {
                    int r = m0 + wm * 64 + fm * 16 + g * 4 + j;
                    int c = n0 + wn * 64 + fn * 16 + lr;
                    outF[(size_t)r * D_ + c] = acc[fm][fn][j] + biasv[fn];
                }
    }
}

// ---------------------------------------------------------------------------
// Kernel 2: flash attention, fp16, swapped-QK^T 32x32x16, KV-split x2,
// ONLINE defer-max softmax (R2-R6-proven structure), register dbuf,
// XCD swizzle.  QK = 4 MFMAs/tile, PV = 4.
// ---------------------------------------------------------------------------
__device__ __forceinline__ void attn_tile(
    const f16x8* kh, const f16x8* vb, uint32_t mw, const f16x8* qf,
    f32x16& o0, f32x16& o1, float& m_run, float& l_run)
{
    const float L2E = 1.4426950408889634f;
    f32x16 s = {};
    __builtin_amdgcn_s_setprio(1);
    s = mfma32f(kh[0], qf[0], s);
    s = mfma32f(kh[1], qf[1], s);
    s = mfma32f(kh[2], qf[2], s);
    s = mfma32f(kh[3], qf[3], s);
    __builtin_amdgcn_s_setprio(0);

#pragma unroll
    for (int r = 0; r < 16; ++r) {
        const int bit = (r & 3) + 8 * (r >> 2);
        if (!((mw >> bit) & 1u)) s[r] = -1e30f;
    }

    // tree row-max (depth 4 + cross-half)
    float t8[8], t4[4];
#pragma unroll
    for (int i = 0; i < 8; ++i) t8[i] = fmaxf(s[i], s[i + 8]);
#pragma unroll
    for (int i = 0; i < 4; ++i) t4[i] = fmaxf(t8[i], t8[i + 4]);
    float pm = fmaxf(fmaxf(t4[0], t4[2]), fmaxf(t4[1], t4[3]));
    pm = fmaxf(pm, __shfl_xor(pm, 32));

    if (__any(pm > m_run + 8.0f)) {        // defer-max rescale (T13)
        float mn  = fmaxf(m_run, pm);
        float fac = exp2f((m_run - mn) * L2E);
        l_run *= fac;
#pragma unroll
        for (int r = 0; r < 16; ++r) { o0[r] *= fac; o1[r] *= fac; }
        m_run = mn;
    }

    float p[16];
#pragma unroll
    for (int r = 0; r < 16; ++r) p[r] = exp2f((s[r] - m_run) * L2E);
    // tree row-sum
    float a8[8], a4[4];
#pragma unroll
    for (int i = 0; i < 8; ++i) a8[i] = p[i] + p[i + 8];
#pragma unroll
    for (int i = 0; i < 4; ++i) a4[i] = a8[i] + a8[i + 4];
    float sum = (a4[0] + a4[2]) + (a4[1] + a4[3]);
    sum += __shfl_xor(sum, 32);
    l_run += sum;

    uint32_t wv[8];
#pragma unroll
    for (int m2 = 0; m2 < 8; ++m2) {
        union { fp16x2 h; uint32_t u; } cv;
        cv.h = __builtin_amdgcn_cvt_pkrtz(p[2 * m2], p[2 * m2 + 1]);
        wv[m2] = cv.u;
    }
    asm("v_permlane32_swap_b32 %0, %1" : "+v"(wv[0]), "+v"(wv[2]));
    asm("v_permlane32_swap_b32 %0, %1" : "+v"(wv[1]), "+v"(wv[3]));
    asm("v_permlane32_swap_b32 %0, %1" : "+v"(wv[4]), "+v"(wv[6]));
    asm("v_permlane32_swap_b32 %0, %1" : "+v"(wv[5]), "+v"(wv[7]));
    union { uint32_t u[4]; f16x8 s8; } pa1, pa2;
    pa1.u[0] = wv[0]; pa1.u[1] = wv[1]; pa1.u[2] = wv[2]; pa1.u[3] = wv[3];
    pa2.u[0] = wv[4]; pa2.u[1] = wv[5]; pa2.u[2] = wv[6]; pa2.u[3] = wv[7];

    __builtin_amdgcn_s_setprio(1);
    o0 = mfma32f(vb[0], pa1.s8, o0);
    o0 = mfma32f(vb[1], pa2.s8, o0);
    o1 = mfma32f(vb[2], pa1.s8, o1);
    o1 = mfma32f(vb[3], pa2.s8, o1);
    __builtin_amdgcn_s_setprio(0);
}

#define LOAD_TILE(kh, vb, mw, kv)                                              \
    do {                                                                       \
        _Pragma("unroll")                                                      \
        for (int c = 0; c < 4; ++c)                                            \
            kh[c] = *(const f16x8*)&Kh[(size_t)((kv) + qi) * DH_ + c * 16 + hl * 8]; \
        vb[0] = *(const f16x8*)&Vh[(size_t)(qi) * T_ + (kv) + hl * 8];         \
        vb[1] = *(const f16x8*)&Vh[(size_t)(qi) * T_ + (kv) + 16 + hl * 8];    \
        vb[2] = *(const f16x8*)&Vh[(size_t)(32 + qi) * T_ + (kv) + hl * 8];    \
        vb[3] = *(const f16x8*)&Vh[(size_t)(32 + qi) * T_ + (kv) + 16 + hl * 8]; \
        mw = mrow[(kv) >> 5] >> (hl * 4);                                      \
    } while (0)

__global__ __launch_bounds__(256, 2) void attn_split_kernel(
    const f16* __restrict__ Qg, const f16* __restrict__ Kg,
    const f16* __restrict__ Vt, const uint32_t* __restrict__ bits,
    f16* __restrict__ Op0, f16* __restrict__ Op1,
    float2* __restrict__ stats)
{
    // bx = [hi2][mid5][lo3]; bh = lo|(hi<<3) -> all 32 (qb,sp) blocks of one
    // bh share bx%8 => same XCD under round-robin dispatch.
    const int bx  = blockIdx.x;
    const int bh  = (bx & 7) | ((bx >> 8) << 3);
    const int mid = (bx >> 3) & 31;
    const int qb  = mid >> 1;
    const int sp  = mid & 1;
    const int b   = bh >> 4, h = bh & 15;
    const int tid = threadIdx.x;
    const int w   = tid >> 6;
    const int l   = tid & 63;
    const int qi  = l & 31;
    const int hl  = l >> 5;
    const int q   = qb * 128 + w * 32 + qi;
    const int kvbase = sp * KVSPAN;

    const size_t hoff = (size_t)(b * H_ + h) * T_ * DH_;
    const f16* Qh = Qg + hoff;
    const f16* Kh = Kg + hoff;
    const f16* Vh = Vt + hoff;                         // [64][T]
    const uint32_t* mrow = bits + ((size_t)b * T_ + q) * (T_ / 32);

    f16x8 qf[4];
#pragma unroll
    for (int c = 0; c < 4; ++c)
        qf[c] = *(const f16x8*)&Qh[(size_t)q * DH_ + c * 16 + hl * 8];

    f32x16 o0 = {}; f32x16 o1 = {};
    float m_run = -1e30f, l_run = 0.0f;

    f16x8 khA[4], vbA[4]; uint32_t mwA;
    f16x8 khB[4], vbB[4]; uint32_t mwB;

    LOAD_TILE(khA, vbA, mwA, kvbase);

    for (int kv0 = kvbase; kv0 < kvbase + KVSPAN; kv0 += 64) {
        LOAD_TILE(khB, vbB, mwB, kv0 + 32);
        attn_tile(khA, vbA, mwA, qf, o0, o1, m_run, l_run);
        LOAD_TILE(khA, vbA, mwA,
                  kvbase + ((kv0 + 64 - kvbase) & (KVSPAN - 1)));  // wraps
        attn_tile(khB, vbB, mwB, qf, o0, o1, m_run, l_run);
    }

    // epilogue: normalized partial O -> Op[sp], stats (m,l) -> stats[sp]
    float inv = 1.0f / l_run;
    float ov[32];
#pragma unroll
    for (int r = 0; r < 16; ++r) { ov[r] = o0[r]; ov[16 + r] = o1[r]; }
    f16* Op = (sp == 0) ? Op0 : Op1;
    f16* prow = Op + ((size_t)bh * T_ + q) * DH_;
#pragma unroll
    for (int dt = 0; dt < 2; ++dt)
#pragma unroll
        for (int g2 = 0; g2 < 4; ++g2) {
            union { f16 h4[4]; uint2 u; } pk;
#pragma unroll
            for (int j = 0; j < 4; ++j)
                pk.h4[j] = (f16)(ov[dt * 16 + 4 * g2 + j] * inv);
            *(uint2*)(prow + dt * 32 + 8 * g2 + 4 * hl) = pk.u;
        }
    if (hl == 0)
        stats[(size_t)sp * (32 * T_) + (size_t)bh * T_ + q] =
            make_float2(m_run, l_run);
}

// ---------------------------------------------------------------------------
// Kernel 2b: combine the two KV-split partials -> comb (fp16 [B,T,D]).
// O = (w0*O0 + w1*O1)/(w0+w1), w_i = l_i * exp2((m_i - m)*log2e).
// ---------------------------------------------------------------------------
__global__ __launch_bounds__(256) void combine_kernel(
    const f16* __restrict__ Op0, const f16* __restrict__ Op1,
    const float2* __restrict__ stats, f16* __restrict__ comb)
{
    const float L2E = 1.4426950408889634f;
    const int row = blockIdx.x * 32 + (threadIdx.x >> 3);   // [0, 32*T_)
    const int dh0 = (threadIdx.x & 7) * 8;
    const int bh = row >> 11, q = row & (T_ - 1);
    const int b = bh >> 4, h = bh & 15;

    float2 s0 = stats[row];
    float2 s1 = stats[32 * T_ + row];
    float m = fmaxf(s0.x, s1.x);
    float w0 = s0.y * exp2f((s0.x - m) * L2E);
    float w1 = s1.y * exp2f((s1.x - m) * L2E);
    float rs = 1.0f / (w0 + w1);
    float a0 = w0 * rs, a1 = w1 * rs;

    f16x8 v0 = *(const f16x8*)(Op0 + (size_t)row * DH_ + dh0);
    f16x8 v1 = *(const f16x8*)(Op1 + (size_t)row * DH_ + dh0);
    f16x8 ou;
#pragma unroll
    for (int i = 0; i < 8; ++i)
        ou[i] = (f16)(a0 * (float)v0[i] + a1 * (float)v1[i]);
    *(f16x8*)(comb + ((size_t)(b * T_ + q)) * D_ + h * DH_ + dh0) = ou;
}

// ---------------------------------------------------------------------------
extern "C" void kernel_launch(void* const* d_in, const int* in_sizes, int n_in,
                              void* d_out, int out_size, void* d_ws, size_t ws_size,
                              hipStream_t stream)
{
    const float* X    = (const float*)d_in[0];
    const int*   mask = (const int*)d_in[1];
    const float* Wq   = (const float*)d_in[2];
    const float* bq   = (const float*)d_in[3];
    const float* Wk   = (const float*)d_in[4];
    const float* bk   = (const float*)d_in[5];
    const float* Wv   = (const float*)d_in[6];
    const float* bv   = (const float*)d_in[7];
    const float* Wo   = (const float*)d_in[8];
    const float* bo   = (const float*)d_in[9];
    float* out = (float*)d_out;

    const size_t SEG  = (size_t)B_ * T_ * D_;   // 4,194,304 elems (8 MiB fp16)
    const size_t WSEG = (size_t)D_ * D_;        // 2 MiB fp16
    f16* wsp = (f16*)d_ws;
    f16* Q    = wsp + 0 * SEG;
    f16* K    = wsp + 1 * SEG;
    f16* Xh   = wsp + 2 * SEG;     // comb aliases Xh after QKV GEMM
    f16* Xl   = wsp + 3 * SEG;     // Op0 aliases Xl after QKV GEMM
    f16* WqT  = wsp + 4 * SEG;
    f16* WkT  = WqT + 1 * WSEG;
    f16* WvT  = WqT + 2 * WSEG;
    f16* WoT  = WqT + 3 * WSEG;
    f16* Op1  = wsp + 5 * SEG;     // ws total: 48 MiB
    f16* comb = Xh;
    f16* Op0  = Xl;
    // d_out scratch: Vt (8 MiB) + bits (1 MiB) + stats (1 MiB); final GEMM
    // overwrites all of d_out.
    f16* Vt = (f16*)d_out;
    uint32_t* bits = (uint32_t*)((char*)d_out + (8u << 20));
    float2* stats  = (float2*)((char*)d_out + (9u << 20));

    dim3 blk(256);
    maskpack_kernel<<<dim3((B_ * T_ * T_) / 256), blk, 0, stream>>>(mask, bits);
    splitx_kernel<<<dim3((B_ * T_ * D_) / 2048), blk, 0, stream>>>(X, Xh, Xl);
    wtr_kernel<<<dim3(16, 16, 4), blk, 0, stream>>>(
        Wq, Wk, Wv, Wo, WqT, WkT, WvT, WoT);
    gemm_kernel<<<dim3(D_ / 128, (B_ * T_) / 128, 3), blk, 0, stream>>>(
        Xh, Xl, 0, WqT, WkT, WvT, WoT,
        bq, bk, bv, bo, Q, K, Vt, out);
    attn_split_kernel<<<dim3(B_ * H_ * (T_ / 128) * NSPLIT), blk, 0, stream>>>(
        Q, K, Vt, bits, Op0, Op1, stats);
    combine_kernel<<<dim3((32 * T_) / 32), blk, 0, stream>>>(
        Op0, Op1, stats, comb);
    gemm_kernel<<<dim3(D_ / 128, (B_ * T_) / 128, 1), blk, 0, stream>>>(
        comb, nullptr, 3, WqT, WkT, WvT, WoT,
        bq, bk, bv, bo, Q, K, Vt, out);
}

// Round 10
// 221.746 us; speedup vs baseline: 2.6401x; 1.0824x over previous
//
#include <hip/hip_runtime.h>
#include <hip/hip_bf16.h>
#include <stdint.h>

typedef _Float16 f16;
typedef __attribute__((ext_vector_type(8))) _Float16 f16x8;
typedef __attribute__((ext_vector_type(2))) __fp16 fp16x2;
typedef __attribute__((ext_vector_type(4))) float f32x4;
typedef __attribute__((ext_vector_type(16))) float f32x16;

#define B_  2
#define T_  2048
#define D_  1024
#define H_  16
#define DH_ 64
#define NSPLIT 2
#define KVSPAN (T_ / NSPLIT)

__device__ __forceinline__ f32x4 mfma16f(f16x8 a, f16x8 b, f32x4 c) {
    return __builtin_amdgcn_mfma_f32_16x16x32_f16(a, b, c, 0, 0, 0);
}
__device__ __forceinline__ f32x16 mfma32f(f16x8 a, f16x8 b, f32x16 c) {
    return __builtin_amdgcn_mfma_f32_32x32x16_f16(a, b, c, 0, 0, 0);
}
__device__ __forceinline__ void gload16(const void* g, void* l) {
    __builtin_amdgcn_global_load_lds(
        (const __attribute__((address_space(1))) uint32_t*)g,
        (__attribute__((address_space(3))) uint32_t*)l, 16, 0, 0);
}

// ---------------------------------------------------------------------------
// Kernel 0: pack int32 mask -> bit mask (1 MB, L2-resident in attn).
// ---------------------------------------------------------------------------
__global__ __launch_bounds__(256) void maskpack_kernel(
    const int* __restrict__ mask, uint32_t* __restrict__ bits)
{
    size_t e = (size_t)blockIdx.x * 256 + threadIdx.x;
    unsigned long long b = __ballot(mask[e] != 0);
    if ((threadIdx.x & 63) == 0)
        *(unsigned long long*)(bits + (e >> 5)) = b;
}

// ---------------------------------------------------------------------------
// Kernel 0b: convert X fp32 -> fp16 (single term; lo-term dropped — logit
// error stays dominated by q/k fp16 rounding).
// ---------------------------------------------------------------------------
__global__ __launch_bounds__(256) void cvtx_kernel(
    const float* __restrict__ X, f16* __restrict__ Xh)
{
    size_t i0 = ((size_t)blockIdx.x * 256 + threadIdx.x) * 8;
    float4 a = *(const float4*)(X + i0);
    float4 b = *(const float4*)(X + i0 + 4);
    float v[8] = {a.x, a.y, a.z, a.w, b.x, b.y, b.z, b.w};
    f16x8 hh;
#pragma unroll
    for (int i = 0; i < 8; ++i) hh[i] = (f16)v[i];
    *(f16x8*)(Xh + i0) = hh;
}

// ---------------------------------------------------------------------------
// Kernel 0c: transpose weights.  W[k][n] fp32 -> WT[n][k] fp16.
// ---------------------------------------------------------------------------
__global__ __launch_bounds__(256) void wtr_kernel(
    const float* __restrict__ Wq, const float* __restrict__ Wk,
    const float* __restrict__ Wv, const float* __restrict__ Wo,
    f16* __restrict__ WqT, f16* __restrict__ WkT,
    f16* __restrict__ WvT, f16* __restrict__ WoT)
{
    __shared__ float s_t[64][65];
    const int zz = blockIdx.z;
    const float* __restrict__ W = (zz == 0) ? Wq : (zz == 1) ? Wk : (zz == 2) ? Wv : Wo;
    const int k0 = blockIdx.y * 64, n0 = blockIdx.x * 64;
    const int t = threadIdx.x;
    const int r = t >> 2, c0 = (t & 3) * 16;

#pragma unroll
    for (int j = 0; j < 4; ++j) {
        float4 v = *(const float4*)(W + (size_t)(k0 + r) * D_ + n0 + c0 + j * 4);
        s_t[r][c0 + j * 4 + 0] = v.x;
        s_t[r][c0 + j * 4 + 1] = v.y;
        s_t[r][c0 + j * 4 + 2] = v.z;
        s_t[r][c0 + j * 4 + 3] = v.w;
    }
    __syncthreads();

    const int n = t >> 2, kc = (t & 3) * 16;
    f16x8 h0, h1;
#pragma unroll
    for (int j = 0; j < 8; ++j) h0[j] = (f16)s_t[kc + j][n];
#pragma unroll
    for (int j = 0; j < 8; ++j) h1[j] = (f16)s_t[kc + 8 + j][n];
    f16* dh = (zz == 0) ? WqT : (zz == 1) ? WkT : (zz == 2) ? WvT : WoT;
    size_t o = (size_t)(n0 + n) * D_ + k0 + kc;
    *(f16x8*)(dh + o) = h0;
    *(f16x8*)(dh + o + 8) = h1;
}

// ---------------------------------------------------------------------------
// Kernel 1: 128x128 fp16 GEMM, BK=32, global_load_lds staging (single-term).
// z: 0=Q (fp16 out, *1/8)  1=K (fp16 out)  2=V (fp16, [B,H,64,T])  3=O (fp32)
// ---------------------------------------------------------------------------
__global__ __launch_bounds__(256) void gemm_kernel(
    const f16* __restrict__ A, int zbase,
    const f16* __restrict__ BqT, const f16* __restrict__ BkT,
    const f16* __restrict__ BvT, const f16* __restrict__ BoT,
    const float* __restrict__ bq, const float* __restrict__ bk,
    const float* __restrict__ bv, const float* __restrict__ bo,
    f16* __restrict__ Q, f16* __restrict__ K,
    f16* __restrict__ Vt, float* __restrict__ outF)
{
    __shared__ f16 sA[128 * 32];
    __shared__ f16 sB[128 * 32];

    const int z = blockIdx.z + zbase;
    const f16* __restrict__ Bm = (z == 0) ? BqT : (z == 1) ? BkT : (z == 2) ? BvT : BoT;
    const float* __restrict__ bias = (z == 0) ? bq : (z == 1) ? bk : (z == 2) ? bv : bo;

    const int m0 = blockIdx.y * 128;
    const int n0 = blockIdx.x * 128;
    const int tid = threadIdx.x;
    const int w = tid >> 6, l = tid & 63;
    const int g = l >> 4, lr = l & 15;
    const int wm = w >> 1, wn = w & 1;

    const int srow = w * 32 + (l >> 2);
    const int skb  = (l & 3) * 8;

    f32x4 acc[4][4] = {};

    for (int k0 = 0; k0 < D_; k0 += 32) {
        __syncthreads();
#pragma unroll
        for (int i = 0; i < 2; ++i) {
            gload16(A  + (size_t)(m0 + srow + i * 16) * D_ + k0 + skb,
                    &sA[w * 1024 + i * 512]);
            gload16(Bm + (size_t)(n0 + srow + i * 16) * D_ + k0 + skb,
                    &sB[w * 1024 + i * 512]);
        }
        __syncthreads();

        f16x8 ah[4], bh[4];
#pragma unroll
        for (int f = 0; f < 4; ++f) {
            ah[f] = *(const f16x8*)&sA[(wm * 64 + f * 16 + lr) * 32 + g * 8];
            bh[f] = *(const f16x8*)&sB[(wn * 64 + f * 16 + lr) * 32 + g * 8];
        }
#pragma unroll
        for (int fm = 0; fm < 4; ++fm)
#pragma unroll
            for (int fn = 0; fn < 4; ++fn)
                acc[fm][fn] = mfma16f(ah[fm], bh[fn], acc[fm][fn]);
    }

    const float scale = (z == 0) ? 0.125f : 1.0f;
    float biasv[4];
#pragma unroll
    for (int f = 0; f < 4; ++f) biasv[f] = bias[n0 + wn * 64 + f * 16 + lr];

    if (z <= 1) {
        f16* Oq = (z == 0) ? Q : K;
#pragma unroll
        for (int fm = 0; fm < 4; ++fm)
#pragma unroll
            for (int fn = 0; fn < 4; ++fn)
#pragma unroll
                for (int j = 0; j < 4; ++j) {
                    int r = m0 + wm * 64 + fm * 16 + g * 4 + j;
                    int c = n0 + wn * 64 + fn * 16 + lr;
                    float v = (acc[fm][fn][j] + biasv[fn]) * scale;
                    int b = r >> 11, t = r & (T_ - 1);
                    int h = (c >> 6) & 15, d = c & 63;
                    Oq[((size_t)(b * H_ + h) * T_ + t) * DH_ + d] = (f16)v;
                }
    } else if (z == 2) {
#pragma unroll
        for (int fm = 0; fm < 4; ++fm)
#pragma unroll
            for (int fn = 0; fn < 4; ++fn) {
                int r0 = m0 + wm * 64 + fm * 16 + g * 4;
                int c  = n0 + wn * 64 + fn * 16 + lr;
                int b = r0 >> 11, t0 = r0 & (T_ - 1);
                int h = (c >> 6) & 15, d = c & 63;
                union { f16 h4[4]; uint2 u; } pk;
#pragma unroll
                for (int j = 0; j < 4; ++j)
                    pk.h4[j] = (f16)(acc[fm][fn][j] + biasv[fn]);
                *(uint2*)&Vt[((size_t)(b * H_ + h) * DH_ + d) * T_ + t0] = pk.u;
            }
    } else {
#pragma unroll
        for (int fm = 0; fm < 4; ++fm)
#pragma unroll
            for (int fn = 0; fn < 4; ++fn)
#pragma unroll
                for (int j = 0; j < 4; ++j) {
                    int r = m0 + wm * 64 + fm * 16 + g * 4 + j;
                    int c = n0 + wn * 64 + fn * 16 + lr;
                    outF[(size_t)r * D_ + c] = acc[fm][fn][j] + biasv[fn];
                }
    }
}

// ---------------------------------------------------------------------------
// Kernel 2: flash attention, fp16, swapped-QK^T 32x32x16, KV-split x2,
// online defer-max softmax.  NO register double-buffer: single kh/vb set
// (saves ~33 VGPRs) so 4 waves/SIMD fit -> TLP hides L2 latency instead.
// ---------------------------------------------------------------------------
__device__ __forceinline__ void attn_tile(
    const f16x8* kh, const f16x8* vb, uint32_t mw, const f16x8* qf,
    f32x16& o0, f32x16& o1, float& m_run, float& l_run)
{
    const float L2E = 1.4426950408889634f;
    f32x16 s = {};
    __builtin_amdgcn_s_setprio(1);
    s = mfma32f(kh[0], qf[0], s);
    s = mfma32f(kh[1], qf[1], s);
    s = mfma32f(kh[2], qf[2], s);
    s = mfma32f(kh[3], qf[3], s);
    __builtin_amdgcn_s_setprio(0);

#pragma unroll
    for (int r = 0; r < 16; ++r) {
        const int bit = (r & 3) + 8 * (r >> 2);
        if (!((mw >> bit) & 1u)) s[r] = -1e30f;
    }

    // tree row-max (depth 4 + cross-half)
    float t8[8], t4[4];
#pragma unroll
    for (int i = 0; i < 8; ++i) t8[i] = fmaxf(s[i], s[i + 8]);
#pragma unroll
    for (int i = 0; i < 4; ++i) t4[i] = fmaxf(t8[i], t8[i + 4]);
    float pm = fmaxf(fmaxf(t4[0], t4[2]), fmaxf(t4[1], t4[3]));
    pm = fmaxf(pm, __shfl_xor(pm, 32));

    if (__any(pm > m_run + 8.0f)) {        // defer-max rescale (T13)
        float mn  = fmaxf(m_run, pm);
        float fac = exp2f((m_run - mn) * L2E);
        l_run *= fac;
#pragma unroll
        for (int r = 0; r < 16; ++r) { o0[r] *= fac; o1[r] *= fac; }
        m_run = mn;
    }

    float p[16];
#pragma unroll
    for (int r = 0; r < 16; ++r) p[r] = exp2f((s[r] - m_run) * L2E);
    // tree row-sum
    float a8[8], a4[4];
#pragma unroll
    for (int i = 0; i < 8; ++i) a8[i] = p[i] + p[i + 8];
#pragma unroll
    for (int i = 0; i < 4; ++i) a4[i] = a8[i] + a8[i + 4];
    float sum = (a4[0] + a4[2]) + (a4[1] + a4[3]);
    sum += __shfl_xor(sum, 32);
    l_run += sum;

    uint32_t wv[8];
#pragma unroll
    for (int m2 = 0; m2 < 8; ++m2) {
        union { fp16x2 h; uint32_t u; } cv;
        cv.h = __builtin_amdgcn_cvt_pkrtz(p[2 * m2], p[2 * m2 + 1]);
        wv[m2] = cv.u;
    }
    asm("v_permlane32_swap_b32 %0, %1" : "+v"(wv[0]), "+v"(wv[2]));
    asm("v_permlane32_swap_b32 %0, %1" : "+v"(wv[1]), "+v"(wv[3]));
    asm("v_permlane32_swap_b32 %0, %1" : "+v"(wv[4]), "+v"(wv[6]));
    asm("v_permlane32_swap_b32 %0, %1" : "+v"(wv[5]), "+v"(wv[7]));
    union { uint32_t u[4]; f16x8 s8; } pa1, pa2;
    pa1.u[0] = wv[0]; pa1.u[1] = wv[1]; pa1.u[2] = wv[2]; pa1.u[3] = wv[3];
    pa2.u[0] = wv[4]; pa2.u[1] = wv[5]; pa2.u[2] = wv[6]; pa2.u[3] = wv[7];

    __builtin_amdgcn_s_setprio(1);
    o0 = mfma32f(vb[0], pa1.s8, o0);
    o0 = mfma32f(vb[1], pa2.s8, o0);
    o1 = mfma32f(vb[2], pa1.s8, o1);
    o1 = mfma32f(vb[3], pa2.s8, o1);
    __builtin_amdgcn_s_setprio(0);
}

__global__ __launch_bounds__(256, 3) void attn_split_kernel(
    const f16* __restrict__ Qg, const f16* __restrict__ Kg,
    const f16* __restrict__ Vt, const uint32_t* __restrict__ bits,
    f16* __restrict__ Op0, f16* __restrict__ Op1,
    float2* __restrict__ stats)
{
    // bx = [hi2][mid5][lo3]; bh = lo|(hi<<3) -> all 32 (qb,sp) blocks of one
    // bh share bx%8 => same XCD under round-robin dispatch.
    const int bx  = blockIdx.x;
    const int bh  = (bx & 7) | ((bx >> 8) << 3);
    const int mid = (bx >> 3) & 31;
    const int qb  = mid >> 1;
    const int sp  = mid & 1;
    const int b   = bh >> 4, h = bh & 15;
    const int tid = threadIdx.x;
    const int w   = tid >> 6;
    const int l   = tid & 63;
    const int qi  = l & 31;
    const int hl  = l >> 5;
    const int q   = qb * 128 + w * 32 + qi;
    const int kvbase = sp * KVSPAN;

    const size_t hoff = (size_t)(b * H_ + h) * T_ * DH_;
    const f16* Qh = Qg + hoff;
    const f16* Kh = Kg + hoff;
    const f16* Vh = Vt + hoff;                         // [64][T]
    const uint32_t* mrow = bits + ((size_t)b * T_ + q) * (T_ / 32);

    f16x8 qf[4];
#pragma unroll
    for (int c = 0; c < 4; ++c)
        qf[c] = *(const f16x8*)&Qh[(size_t)q * DH_ + c * 16 + hl * 8];

    f32x16 o0 = {}; f32x16 o1 = {};
    float m_run = -1e30f, l_run = 0.0f;

    for (int kv0 = kvbase; kv0 < kvbase + KVSPAN; kv0 += 32) {
        f16x8 kh[4], vb[4]; uint32_t mw;
#pragma unroll
        for (int c = 0; c < 4; ++c)
            kh[c] = *(const f16x8*)&Kh[(size_t)(kv0 + qi) * DH_ + c * 16 + hl * 8];
        vb[0] = *(const f16x8*)&Vh[(size_t)(qi) * T_ + kv0 + hl * 8];
        vb[1] = *(const f16x8*)&Vh[(size_t)(qi) * T_ + kv0 + 16 + hl * 8];
        vb[2] = *(const f16x8*)&Vh[(size_t)(32 + qi) * T_ + kv0 + hl * 8];
        vb[3] = *(const f16x8*)&Vh[(size_t)(32 + qi) * T_ + kv0 + 16 + hl * 8];
        mw = mrow[kv0 >> 5] >> (hl * 4);
        attn_tile(kh, vb, mw, qf, o0, o1, m_run, l_run);
    }

    // epilogue: normalized partial O -> Op[sp], stats (m,l) -> stats[sp]
    float inv = 1.0f / l_run;
    float ov[32];
#pragma unroll
    for (int r = 0; r < 16; ++r) { ov[r] = o0[r]; ov[16 + r] = o1[r]; }
    f16* Op = (sp == 0) ? Op0 : Op1;
    f16* prow = Op + ((size_t)bh * T_ + q) * DH_;
#pragma unroll
    for (int dt = 0; dt < 2; ++dt)
#pragma unroll
        for (int g2 = 0; g2 < 4; ++g2) {
            union { f16 h4[4]; uint2 u; } pk;
#pragma unroll
            for (int j = 0; j < 4; ++j)
                pk.h4[j] = (f16)(ov[dt * 16 + 4 * g2 + j] * inv);
            *(uint2*)(prow + dt * 32 + 8 * g2 + 4 * hl) = pk.u;
        }
    if (hl == 0)
        stats[(size_t)sp * (32 * T_) + (size_t)bh * T_ + q] =
            make_float2(m_run, l_run);
}

// ---------------------------------------------------------------------------
// Kernel 2b: combine the two KV-split partials -> comb (fp16 [B,T,D]).
// O = (w0*O0 + w1*O1)/(w0+w1), w_i = l_i * exp2((m_i - m)*log2e).
// ---------------------------------------------------------------------------
__global__ __launch_bounds__(256) void combine_kernel(
    const f16* __restrict__ Op0, const f16* __restrict__ Op1,
    const float2* __restrict__ stats, f16* __restrict__ comb)
{
    const float L2E = 1.4426950408889634f;
    const int row = blockIdx.x * 32 + (threadIdx.x >> 3);   // [0, 32*T_)
    const int dh0 = (threadIdx.x & 7) * 8;
    const int bh = row >> 11, q = row & (T_ - 1);
    const int b = bh >> 4, h = bh & 15;

    float2 s0 = stats[row];
    float2 s1 = stats[32 * T_ + row];
    float m = fmaxf(s0.x, s1.x);
    float w0 = s0.y * exp2f((s0.x - m) * L2E);
    float w1 = s1.y * exp2f((s1.x - m) * L2E);
    float rs = 1.0f / (w0 + w1);
    float a0 = w0 * rs, a1 = w1 * rs;

    f16x8 v0 = *(const f16x8*)(Op0 + (size_t)row * DH_ + dh0);
    f16x8 v1 = *(const f16x8*)(Op1 + (size_t)row * DH_ + dh0);
    f16x8 ou;
#pragma unroll
    for (int i = 0; i < 8; ++i)
        ou[i] = (f16)(a0 * (float)v0[i] + a1 * (float)v1[i]);
    *(f16x8*)(comb + ((size_t)(b * T_ + q)) * D_ + h * DH_ + dh0) = ou;
}

// ---------------------------------------------------------------------------
extern "C" void kernel_launch(void* const* d_in, const int* in_sizes, int n_in,
                              void* d_out, int out_size, void* d_ws, size_t ws_size,
                              hipStream_t stream)
{
    const float* X    = (const float*)d_in[0];
    const int*   mask = (const int*)d_in[1];
    const float* Wq   = (const float*)d_in[2];
    const float* bq   = (const float*)d_in[3];
    const float* Wk   = (const float*)d_in[4];
    const float* bk   = (const float*)d_in[5];
    const float* Wv   = (const float*)d_in[6];
    const float* bv   = (const float*)d_in[7];
    const float* Wo   = (const float*)d_in[8];
    const float* bo   = (const float*)d_in[9];
    float* out = (float*)d_out;

    const size_t SEG  = (size_t)B_ * T_ * D_;   // 4,194,304 elems (8 MiB fp16)
    const size_t WSEG = (size_t)D_ * D_;        // 2 MiB fp16
    f16* wsp = (f16*)d_ws;
    f16* Q    = wsp + 0 * SEG;
    f16* K    = wsp + 1 * SEG;
    f16* Xh   = wsp + 2 * SEG;     // comb aliases Xh after QKV GEMM
    f16* Op0  = wsp + 3 * SEG;
    f16* WqT  = wsp + 4 * SEG;
    f16* WkT  = WqT + 1 * WSEG;
    f16* WvT  = WqT + 2 * WSEG;
    f16* WoT  = WqT + 3 * WSEG;
    f16* Op1  = wsp + 5 * SEG;     // ws total: 48 MiB
    f16* comb = Xh;
    // d_out scratch: Vt (8 MiB) + bits (1 MiB) + stats (1 MiB); final GEMM
    // overwrites all of d_out.
    f16* Vt = (f16*)d_out;
    uint32_t* bits = (uint32_t*)((char*)d_out + (8u << 20));
    float2* stats  = (float2*)((char*)d_out + (9u << 20));

    dim3 blk(256);
    maskpack_kernel<<<dim3((B_ * T_ * T_) / 256), blk, 0, stream>>>(mask, bits);
    cvtx_kernel<<<dim3((B_ * T_ * D_) / 2048), blk, 0, stream>>>(X, Xh);
    wtr_kernel<<<dim3(16, 16, 4), blk, 0, stream>>>(
        Wq, Wk, Wv, Wo, WqT, WkT, WvT, WoT);
    gemm_kernel<<<dim3(D_ / 128, (B_ * T_) / 128, 3), blk, 0, stream>>>(
        Xh, 0, WqT, WkT, WvT, WoT,
        bq, bk, bv, bo, Q, K, Vt, out);
    attn_split_kernel<<<dim3(B_ * H_ * (T_ / 128) * NSPLIT), blk, 0, stream>>>(
        Q, K, Vt, bits, Op0, Op1, stats);
    combine_kernel<<<dim3((32 * T_) / 32), blk, 0, stream>>>(
        Op0, Op1, stats, comb);
    gemm_kernel<<<dim3(D_ / 128, (B_ * T_) / 128, 1), blk, 0, stream>>>(
        comb, 3, WqT, WkT, WvT, WoT,
        bq, bk, bv, bo, Q, K, Vt, out);
}

// Round 12
// 220.975 us; speedup vs baseline: 2.6493x; 1.0035x over previous
//
#include <hip/hip_runtime.h>
#include <hip/hip_bf16.h>
#include <stdint.h>

typedef _Float16 f16;
typedef __attribute__((ext_vector_type(8))) _Float16 f16x8;
typedef __attribute__((ext_vector_type(2))) __fp16 fp16x2;
typedef __attribute__((ext_vector_type(4))) float f32x4;
typedef __attribute__((ext_vector_type(16))) float f32x16;

#define B_  2
#define T_  2048
#define D_  1024
#define H_  16
#define DH_ 64
#define NSPLIT 2
#define KVSPAN (T_ / NSPLIT)

__device__ __forceinline__ f32x4 mfma16f(f16x8 a, f16x8 b, f32x4 c) {
    return __builtin_amdgcn_mfma_f32_16x16x32_f16(a, b, c, 0, 0, 0);
}
__device__ __forceinline__ f32x16 mfma32f(f16x8 a, f16x8 b, f32x16 c) {
    return __builtin_amdgcn_mfma_f32_32x32x16_f16(a, b, c, 0, 0, 0);
}
__device__ __forceinline__ void gload16(const void* g, void* l) {
    __builtin_amdgcn_global_load_lds(
        (const __attribute__((address_space(1))) uint32_t*)g,
        (__attribute__((address_space(3))) uint32_t*)l, 16, 0, 0);
}
// cross-half (lane ^ 32) max/sum via v_permlane32_swap (VALU) instead of
// __shfl_xor -> ds_bpermute (LDS pipe, ~120cy).  HAZARD FIX vs R11: gfx950
// requires wait state(s) between a VALU write and a permlane_swap reading it;
// inside one asm block the compiler can't insert them -> explicit s_nop 1.
__device__ __forceinline__ float xmax32(float x) {
    float a, b;
    asm("v_mov_b32 %0, %2\n\t"
        "v_mov_b32 %1, %2\n\t"
        "s_nop 1\n\t"
        "v_permlane32_swap_b32 %0, %1\n\t"
        "s_nop 1\n\t"
        "v_max_f32 %0, %0, %1"
        : "=&v"(a), "=&v"(b) : "v"(x));
    return a;
}
__device__ __forceinline__ float xsum32(float x) {
    float a, b;
    asm("v_mov_b32 %0, %2\n\t"
        "v_mov_b32 %1, %2\n\t"
        "s_nop 1\n\t"
        "v_permlane32_swap_b32 %0, %1\n\t"
        "s_nop 1\n\t"
        "v_add_f32 %0, %0, %1"
        : "=&v"(a), "=&v"(b) : "v"(x));
    return a;
}

// ---------------------------------------------------------------------------
// Kernel 0: pack int32 mask -> bit mask (1 MB, L2-resident in attn).
// ---------------------------------------------------------------------------
__global__ __launch_bounds__(256) void maskpack_kernel(
    const int* __restrict__ mask, uint32_t* __restrict__ bits)
{
    size_t e = (size_t)blockIdx.x * 256 + threadIdx.x;
    unsigned long long b = __ballot(mask[e] != 0);
    if ((threadIdx.x & 63) == 0)
        *(unsigned long long*)(bits + (e >> 5)) = b;
}

// ---------------------------------------------------------------------------
// Kernel 0b: convert X fp32 -> fp16.
// ---------------------------------------------------------------------------
__global__ __launch_bounds__(256) void cvtx_kernel(
    const float* __restrict__ X, f16* __restrict__ Xh)
{
    size_t i0 = ((size_t)blockIdx.x * 256 + threadIdx.x) * 8;
    float4 a = *(const float4*)(X + i0);
    float4 b = *(const float4*)(X + i0 + 4);
    float v[8] = {a.x, a.y, a.z, a.w, b.x, b.y, b.z, b.w};
    f16x8 hh;
#pragma unroll
    for (int i = 0; i < 8; ++i) hh[i] = (f16)v[i];
    *(f16x8*)(Xh + i0) = hh;
}

// ---------------------------------------------------------------------------
// Kernel 0c: transpose weights.  W[k][n] fp32 -> WT[n][k] fp16.
// ---------------------------------------------------------------------------
__global__ __launch_bounds__(256) void wtr_kernel(
    const float* __restrict__ Wq, const float* __restrict__ Wk,
    const float* __restrict__ Wv, const float* __restrict__ Wo,
    f16* __restrict__ WqT, f16* __restrict__ WkT,
    f16* __restrict__ WvT, f16* __restrict__ WoT)
{
    __shared__ float s_t[64][65];
    const int zz = blockIdx.z;
    const float* __restrict__ W = (zz == 0) ? Wq : (zz == 1) ? Wk : (zz == 2) ? Wv : Wo;
    const int k0 = blockIdx.y * 64, n0 = blockIdx.x * 64;
    const int t = threadIdx.x;
    const int r = t >> 2, c0 = (t & 3) * 16;

#pragma unroll
    for (int j = 0; j < 4; ++j) {
        float4 v = *(const float4*)(W + (size_t)(k0 + r) * D_ + n0 + c0 + j * 4);
        s_t[r][c0 + j * 4 + 0] = v.x;
        s_t[r][c0 + j * 4 + 1] = v.y;
        s_t[r][c0 + j * 4 + 2] = v.z;
        s_t[r][c0 + j * 4 + 3] = v.w;
    }
    __syncthreads();

    const int n = t >> 2, kc = (t & 3) * 16;
    f16x8 h0, h1;
#pragma unroll
    for (int j = 0; j < 8; ++j) h0[j] = (f16)s_t[kc + j][n];
#pragma unroll
    for (int j = 0; j < 8; ++j) h1[j] = (f16)s_t[kc + 8 + j][n];
    f16* dh = (zz == 0) ? WqT : (zz == 1) ? WkT : (zz == 2) ? WvT : WoT;
    size_t o = (size_t)(n0 + n) * D_ + k0 + kc;
    *(f16x8*)(dh + o) = h0;
    *(f16x8*)(dh + o + 8) = h1;
}

// ---------------------------------------------------------------------------
// Kernel 1: 128x128 fp16 GEMM, BK=32, global_load_lds staging.
// z: 0=Q (fp16 out, *1/8)  1=K (fp16 out)  2=V (fp16, [B,H,64,T])  3=O (fp32)
// ---------------------------------------------------------------------------
__global__ __launch_bounds__(256) void gemm_kernel(
    const f16* __restrict__ A, int zbase,
    const f16* __restrict__ BqT, const f16* __restrict__ BkT,
    const f16* __restrict__ BvT, const f16* __restrict__ BoT,
    const float* __restrict__ bq, const float* __restrict__ bk,
    const float* __restrict__ bv, const float* __restrict__ bo,
    f16* __restrict__ Q, f16* __restrict__ K,
    f16* __restrict__ Vt, float* __restrict__ outF)
{
    __shared__ f16 sA[128 * 32];
    __shared__ f16 sB[128 * 32];

    const int z = blockIdx.z + zbase;
    const f16* __restrict__ Bm = (z == 0) ? BqT : (z == 1) ? BkT : (z == 2) ? BvT : BoT;
    const float* __restrict__ bias = (z == 0) ? bq : (z == 1) ? bk : (z == 2) ? bv : bo;

    const int m0 = blockIdx.y * 128;
    const int n0 = blockIdx.x * 128;
    const int tid = threadIdx.x;
    const int w = tid >> 6, l = tid & 63;
    const int g = l >> 4, lr = l & 15;
    const int wm = w >> 1, wn = w & 1;

    const int srow = w * 32 + (l >> 2);
    const int skb  = (l & 3) * 8;

    f32x4 acc[4][4] = {};

    for (int k0 = 0; k0 < D_; k0 += 32) {
        __syncthreads();
#pragma unroll
        for (int i = 0; i < 2; ++i) {
            gload16(A  + (size_t)(m0 + srow + i * 16) * D_ + k0 + skb,
                    &sA[w * 1024 + i * 512]);
            gload16(Bm + (size_t)(n0 + srow + i * 16) * D_ + k0 + skb,
                    &sB[w * 1024 + i * 512]);
        }
        __syncthreads();

        f16x8 ah[4], bh[4];
#pragma unroll
        for (int f = 0; f < 4; ++f) {
            ah[f] = *(const f16x8*)&sA[(wm * 64 + f * 16 + lr) * 32 + g * 8];
            bh[f] = *(const f16x8*)&sB[(wn * 64 + f * 16 + lr) * 32 + g * 8];
        }
#pragma unroll
        for (int fm = 0; fm < 4; ++fm)
#pragma unroll
            for (int fn = 0; fn < 4; ++fn)
                acc[fm][fn] = mfma16f(ah[fm], bh[fn], acc[fm][fn]);
    }

    const float scale = (z == 0) ? 0.125f : 1.0f;
    float biasv[4];
#pragma unroll
    for (int f = 0; f < 4; ++f) biasv[f] = bias[n0 + wn * 64 + f * 16 + lr];

    if (z <= 1) {
        f16* Oq = (z == 0) ? Q : K;
#pragma unroll
        for (int fm = 0; fm < 4; ++fm)
#pragma unroll
            for (int fn = 0; fn < 4; ++fn)
#pragma unroll
                for (int j = 0; j < 4; ++j) {
                    int r = m0 + wm * 64 + fm * 16 + g * 4 + j;
                    int c = n0 + wn * 64 + fn * 16 + lr;
                    float v = (acc[fm][fn][j] + biasv[fn]) * scale;
                    int b = r >> 11, t = r & (T_ - 1);
                    int h = (c >> 6) & 15, d = c & 63;
                    Oq[((size_t)(b * H_ + h) * T_ + t) * DH_ + d] = (f16)v;
                }
    } else if (z == 2) {
#pragma unroll
        for (int fm = 0; fm < 4; ++fm)
#pragma unroll
            for (int fn = 0; fn < 4; ++fn) {
                int r0 = m0 + wm * 64 + fm * 16 + g * 4;
                int c  = n0 + wn * 64 + fn * 16 + lr;
                int b = r0 >> 11, t0 = r0 & (T_ - 1);
                int h = (c >> 6) & 15, d = c & 63;
                union { f16 h4[4]; uint2 u; } pk;
#pragma unroll
                for (int j = 0; j < 4; ++j)
                    pk.h4[j] = (f16)(acc[fm][fn][j] + biasv[fn]);
                *(uint2*)&Vt[((size_t)(b * H_ + h) * DH_ + d) * T_ + t0] = pk.u;
            }
    } else {
#pragma unroll
        for (int fm = 0; fm < 4; ++fm)
#pragma unroll
            for (int fn = 0; fn < 4; ++fn)
#pragma unroll
                for (int j = 0; j < 4; ++j) {
                    int r = m0 + wm * 64 + fm * 16 + g * 4 + j;
                    int c = n0 + wn * 64 + fn * 16 + lr;
                    outF[(size_t)r * D_ + c] = acc[fm][fn][j] + biasv[fn];
                }
    }
}

// ---------------------------------------------------------------------------
// Kernel 2: flash attention, fp16, swapped-QK^T 32x32x16, KV-split x2,
// online defer-max softmax.  R10 structure exactly (mask -> s BEFORE max);
// only change: cross-half max/sum via hazard-safe permlane32_swap helpers.
// ---------------------------------------------------------------------------
__device__ __forceinline__ void attn_tile(
    const f16x8* kh, const f16x8* vb, uint32_t mw, const f16x8* qf,
    f32x16& o0, f32x16& o1, float& m_run, float& l_run)
{
    const float L2E = 1.4426950408889634f;
    f32x16 s = {};
    __builtin_amdgcn_s_setprio(1);
    s = mfma32f(kh[0], qf[0], s);
    s = mfma32f(kh[1], qf[1], s);
    s = mfma32f(kh[2], qf[2], s);
    s = mfma32f(kh[3], qf[3], s);
    __builtin_amdgcn_s_setprio(0);

#pragma unroll
    for (int r = 0; r < 16; ++r) {
        const int bit = (r & 3) + 8 * (r >> 2);
        if (!((mw >> bit) & 1u)) s[r] = -1e30f;
    }

    // tree row-max (depth 4) + cross-half via permlane (VALU, not LDS)
    float t8[8], t4[4];
#pragma unroll
    for (int i = 0; i < 8; ++i) t8[i] = fmaxf(s[i], s[i + 8]);
#pragma unroll
    for (int i = 0; i < 4; ++i) t4[i] = fmaxf(t8[i], t8[i + 4]);
    float pm = fmaxf(fmaxf(t4[0], t4[2]), fmaxf(t4[1], t4[3]));
    pm = xmax32(pm);

    if (__any(pm > m_run + 8.0f)) {        // defer-max rescale (T13)
        float mn  = fmaxf(m_run, pm);
        float fac = exp2f((m_run - mn) * L2E);
        l_run *= fac;
#pragma unroll
        for (int r = 0; r < 16; ++r) { o0[r] *= fac; o1[r] *= fac; }
        m_run = mn;
    }

    float p[16];
#pragma unroll
    for (int r = 0; r < 16; ++r) p[r] = exp2f((s[r] - m_run) * L2E);
    // tree row-sum + cross-half via permlane
    float a8[8], a4[4];
#pragma unroll
    for (int i = 0; i < 8; ++i) a8[i] = p[i] + p[i + 8];
#pragma unroll
    for (int i = 0; i < 4; ++i) a4[i] = a8[i] + a8[i + 4];
    float sum = (a4[0] + a4[2]) + (a4[1] + a4[3]);
    sum = xsum32(sum);
    l_run += sum;

    uint32_t wv[8];
#pragma unroll
    for (int m2 = 0; m2 < 8; ++m2) {
        union { fp16x2 h; uint32_t u; } cv;
        cv.h = __builtin_amdgcn_cvt_pkrtz(p[2 * m2], p[2 * m2 + 1]);
        wv[m2] = cv.u;
    }
    asm("v_permlane32_swap_b32 %0, %1" : "+v"(wv[0]), "+v"(wv[2]));
    asm("v_permlane32_swap_b32 %0, %1" : "+v"(wv[1]), "+v"(wv[3]));
    asm("v_permlane32_swap_b32 %0, %1" : "+v"(wv[4]), "+v"(wv[6]));
    asm("v_permlane32_swap_b32 %0, %1" : "+v"(wv[5]), "+v"(wv[7]));
    union { uint32_t u[4]; f16x8 s8; } pa1, pa2;
    pa1.u[0] = wv[0]; pa1.u[1] = wv[1]; pa1.u[2] = wv[2]; pa1.u[3] = wv[3];
    pa2.u[0] = wv[4]; pa2.u[1] = wv[5]; pa2.u[2] = wv[6]; pa2.u[3] = wv[7];

    __builtin_amdgcn_s_setprio(1);
    o0 = mfma32f(vb[0], pa1.s8, o0);
    o0 = mfma32f(vb[1], pa2.s8, o0);
    o1 = mfma32f(vb[2], pa1.s8, o1);
    o1 = mfma32f(vb[3], pa2.s8, o1);
    __builtin_amdgcn_s_setprio(0);
}

__global__ __launch_bounds__(256, 3) void attn_split_kernel(
    const f16* __restrict__ Qg, const f16* __restrict__ Kg,
    const f16* __restrict__ Vt, const uint32_t* __restrict__ bits,
    f16* __restrict__ Op0, f16* __restrict__ Op1,
    float2* __restrict__ stats)
{
    // bx = [hi2][mid5][lo3]; bh = lo|(hi<<3) -> all 32 (qb,sp) blocks of one
    // bh share bx%8 => same XCD under round-robin dispatch.
    const int bx  = blockIdx.x;
    const int bh  = (bx & 7) | ((bx >> 8) << 3);
    const int mid = (bx >> 3) & 31;
    const int qb  = mid >> 1;
    const int sp  = mid & 1;
    const int b   = bh >> 4, h = bh & 15;
    const int tid = threadIdx.x;
    const int w   = tid >> 6;
    const int l   = tid & 63;
    const int qi  = l & 31;
    const int hl  = l >> 5;
    const int q   = qb * 128 + w * 32 + qi;
    const int kvbase = sp * KVSPAN;

    const size_t hoff = (size_t)(b * H_ + h) * T_ * DH_;
    const f16* Qh = Qg + hoff;
    const f16* Kh = Kg + hoff;
    const f16* Vh = Vt + hoff;                         // [64][T]
    const uint32_t* mrow = bits + ((size_t)b * T_ + q) * (T_ / 32);

    f16x8 qf[4];
#pragma unroll
    for (int c = 0; c < 4; ++c)
        qf[c] = *(const f16x8*)&Qh[(size_t)q * DH_ + c * 16 + hl * 8];

    f32x16 o0 = {}; f32x16 o1 = {};
    float m_run = -1e30f, l_run = 0.0f;

    for (int kv0 = kvbase; kv0 < kvbase + KVSPAN; kv0 += 32) {
        f16x8 kh[4], vb[4]; uint32_t mw;
        mw = mrow[kv0 >> 5] >> (hl * 4);
#pragma unroll
        for (int c = 0; c < 4; ++c)
            kh[c] = *(const f16x8*)&Kh[(size_t)(kv0 + qi) * DH_ + c * 16 + hl * 8];
        vb[0] = *(const f16x8*)&Vh[(size_t)(qi) * T_ + kv0 + hl * 8];
        vb[1] = *(const f16x8*)&Vh[(size_t)(qi) * T_ + kv0 + 16 + hl * 8];
        vb[2] = *(const f16x8*)&Vh[(size_t)(32 + qi) * T_ + kv0 + hl * 8];
        vb[3] = *(const f16x8*)&Vh[(size_t)(32 + qi) * T_ + kv0 + 16 + hl * 8];
        attn_tile(kh, vb, mw, qf, o0, o1, m_run, l_run);
    }

    // epilogue: normalized partial O -> Op[sp], stats (m,l) -> stats[sp]
    float inv = 1.0f / l_run;
    float ov[32];
#pragma unroll
    for (int r = 0; r < 16; ++r) { ov[r] = o0[r]; ov[16 + r] = o1[r]; }
    f16* Op = (sp == 0) ? Op0 : Op1;
    f16* prow = Op + ((size_t)bh * T_ + q) * DH_;
#pragma unroll
    for (int dt = 0; dt < 2; ++dt)
#pragma unroll
        for (int g2 = 0; g2 < 4; ++g2) {
            union { f16 h4[4]; uint2 u; } pk;
#pragma unroll
            for (int j = 0; j < 4; ++j)
                pk.h4[j] = (f16)(ov[dt * 16 + 4 * g2 + j] * inv);
            *(uint2*)(prow + dt * 32 + 8 * g2 + 4 * hl) = pk.u;
        }
    if (hl == 0)
        stats[(size_t)sp * (32 * T_) + (size_t)bh * T_ + q] =
            make_float2(m_run, l_run);
}

// ---------------------------------------------------------------------------
// Kernel 2b: combine the two KV-split partials -> comb (fp16 [B,T,D]).
// O = (w0*O0 + w1*O1)/(w0+w1), w_i = l_i * exp2((m_i - m)*log2e).
// ---------------------------------------------------------------------------
__global__ __launch_bounds__(256) void combine_kernel(
    const f16* __restrict__ Op0, const f16* __restrict__ Op1,
    const float2* __restrict__ stats, f16* __restrict__ comb)
{
    const float L2E = 1.4426950408889634f;
    const int row = blockIdx.x * 32 + (threadIdx.x >> 3);   // [0, 32*T_)
    const int dh0 = (threadIdx.x & 7) * 8;
    const int bh = row >> 11, q = row & (T_ - 1);
    const int b = bh >> 4, h = bh & 15;

    float2 s0 = stats[row];
    float2 s1 = stats[32 * T_ + row];
    float m = fmaxf(s0.x, s1.x);
    float w0 = s0.y * exp2f((s0.x - m) * L2E);
    float w1 = s1.y * exp2f((s1.x - m) * L2E);
    float rs = 1.0f / (w0 + w1);
    float a0 = w0 * rs, a1 = w1 * rs;

    f16x8 v0 = *(const f16x8*)(Op0 + (size_t)row * DH_ + dh0);
    f16x8 v1 = *(const f16x8*)(Op1 + (size_t)row * DH_ + dh0);
    f16x8 ou;
#pragma unroll
    for (int i = 0; i < 8; ++i)
        ou[i] = (f16)(a0 * (float)v0[i] + a1 * (float)v1[i]);
    *(f16x8*)(comb + ((size_t)(b * T_ + q)) * D_ + h * DH_ + dh0) = ou;
}

// ---------------------------------------------------------------------------
extern "C" void kernel_launch(void* const* d_in, const int* in_sizes, int n_in,
                              void* d_out, int out_size, void* d_ws, size_t ws_size,
                              hipStream_t stream)
{
    const float* X    = (const float*)d_in[0];
    const int*   mask = (const int*)d_in[1];
    const float* Wq   = (const float*)d_in[2];
    const float* bq   = (const float*)d_in[3];
    const float* Wk   = (const float*)d_in[4];
    const float* bk   = (const float*)d_in[5];
    const float* Wv   = (const float*)d_in[6];
    const float* bv   = (const float*)d_in[7];
    const float* Wo   = (const float*)d_in[8];
    const float* bo   = (const float*)d_in[9];
    float* out = (float*)d_out;

    const size_t SEG  = (size_t)B_ * T_ * D_;   // 4,194,304 elems (8 MiB fp16)
    const size_t WSEG = (size_t)D_ * D_;        // 2 MiB fp16
    f16* wsp = (f16*)d_ws;
    f16* Q    = wsp + 0 * SEG;
    f16* K    = wsp + 1 * SEG;
    f16* Xh   = wsp + 2 * SEG;     // comb aliases Xh after QKV GEMM
    f16* Op0  = wsp + 3 * SEG;
    f16* WqT  = wsp + 4 * SEG;
    f16* WkT  = WqT + 1 * WSEG;
    f16* WvT  = WqT + 2 * WSEG;
    f16* WoT  = WqT + 3 * WSEG;
    f16* Op1  = wsp + 5 * SEG;     // ws total: 48 MiB
    f16* comb = Xh;
    // d_out scratch: Vt (8 MiB) + bits (1 MiB) + stats (1 MiB); final GEMM
    // overwrites all of d_out.
    f16* Vt = (f16*)d_out;
    uint32_t* bits = (uint32_t*)((char*)d_out + (8u << 20));
    float2* stats  = (float2*)((char*)d_out + (9u << 20));

    dim3 blk(256);
    maskpack_kernel<<<dim3((B_ * T_ * T_) / 256), blk, 0, stream>>>(mask, bits);
    cvtx_kernel<<<dim3((B_ * T_ * D_) / 2048), blk, 0, stream>>>(X, Xh);
    wtr_kernel<<<dim3(16, 16, 4), blk, 0, stream>>>(
        Wq, Wk, Wv, Wo, WqT, WkT, WvT, WoT);
    gemm_kernel<<<dim3(D_ / 128, (B_ * T_) / 128, 3), blk, 0, stream>>>(
        Xh, 0, WqT, WkT, WvT, WoT,
        bq, bk, bv, bo, Q, K, Vt, out);
    attn_split_kernel<<<dim3(B_ * H_ * (T_ / 128) * NSPLIT), blk, 0, stream>>>(
        Q, K, Vt, bits, Op0, Op1, stats);
    combine_kernel<<<dim3((32 * T_) / 32), blk, 0, stream>>>(
        Op0, Op1, stats, comb);
    gemm_kernel<<<dim3(D_ / 128, (B_ * T_) / 128, 1), blk, 0, stream>>>(
        comb, 3, WqT, WkT, WvT, WoT,
        bq, bk, bv, bo, Q, K, Vt, out);
}

// Round 13
// 161.722 us; speedup vs baseline: 3.6199x; 1.3664x over previous
//
#include <hip/hip_runtime.h>
#include <hip/hip_bf16.h>
#include <stdint.h>

typedef _Float16 f16;
typedef __attribute__((ext_vector_type(8))) _Float16 f16x8;
typedef __attribute__((ext_vector_type(2))) __fp16 fp16x2;
typedef __attribute__((ext_vector_type(4))) float f32x4;
typedef __attribute__((ext_vector_type(16))) float f32x16;

#define B_  2
#define T_  2048
#define D_  1024
#define H_  16
#define DH_ 64
#define NSPLIT 2
#define KVSPAN (T_ / NSPLIT)

__device__ __forceinline__ f32x4 mfma16f(f16x8 a, f16x8 b, f32x4 c) {
    return __builtin_amdgcn_mfma_f32_16x16x32_f16(a, b, c, 0, 0, 0);
}
__device__ __forceinline__ f32x16 mfma32f(f16x8 a, f16x8 b, f32x16 c) {
    return __builtin_amdgcn_mfma_f32_32x32x16_f16(a, b, c, 0, 0, 0);
}
__device__ __forceinline__ void gload16(const void* g, void* l) {
    __builtin_amdgcn_global_load_lds(
        (const __attribute__((address_space(1))) uint32_t*)g,
        (__attribute__((address_space(3))) uint32_t*)l, 16, 0, 0);
}
// cross-half (lane ^ 32) max/sum via v_permlane32_swap (hazard-safe, R12).
__device__ __forceinline__ float xmax32(float x) {
    float a, b;
    asm("v_mov_b32 %0, %2\n\t"
        "v_mov_b32 %1, %2\n\t"
        "s_nop 1\n\t"
        "v_permlane32_swap_b32 %0, %1\n\t"
        "s_nop 1\n\t"
        "v_max_f32 %0, %0, %1"
        : "=&v"(a), "=&v"(b) : "v"(x));
    return a;
}
__device__ __forceinline__ float xsum32(float x) {
    float a, b;
    asm("v_mov_b32 %0, %2\n\t"
        "v_mov_b32 %1, %2\n\t"
        "s_nop 1\n\t"
        "v_permlane32_swap_b32 %0, %1\n\t"
        "s_nop 1\n\t"
        "v_add_f32 %0, %0, %1"
        : "=&v"(a), "=&v"(b) : "v"(x));
    return a;
}

// ---------------------------------------------------------------------------
// Kernel 0: pack int32 mask -> TRANSPOSED bit mask bitsT[b][word][q] so the
// attn per-tile mask read is coalesced (lane qi -> consecutive dwords).
// ---------------------------------------------------------------------------
__global__ __launch_bounds__(256) void maskpack_kernel(
    const int* __restrict__ mask, uint32_t* __restrict__ bitsT)
{
    size_t e = (size_t)blockIdx.x * 256 + threadIdx.x;   // [B][T][T] linear
    unsigned long long bb = __ballot(mask[e] != 0);
    if ((threadIdx.x & 63) == 0) {
        size_t r = e >> 11;              // b*T + q
        int b = (int)(r >> 11), q = (int)(r & (T_ - 1));
        int k = (int)(e & (T_ - 1));
        int w0 = k >> 5;
        size_t base = (size_t)b * (64 * T_) + q;
        bitsT[base + (size_t)w0 * T_]       = (uint32_t)bb;
        bitsT[base + (size_t)(w0 + 1) * T_] = (uint32_t)(bb >> 32);
    }
}

// ---------------------------------------------------------------------------
// Kernel 0b: convert X fp32 -> fp16.
// ---------------------------------------------------------------------------
__global__ __launch_bounds__(256) void cvtx_kernel(
    const float* __restrict__ X, f16* __restrict__ Xh)
{
    size_t i0 = ((size_t)blockIdx.x * 256 + threadIdx.x) * 8;
    float4 a = *(const float4*)(X + i0);
    float4 b = *(const float4*)(X + i0 + 4);
    float v[8] = {a.x, a.y, a.z, a.w, b.x, b.y, b.z, b.w};
    f16x8 hh;
#pragma unroll
    for (int i = 0; i < 8; ++i) hh[i] = (f16)v[i];
    *(f16x8*)(Xh + i0) = hh;
}

// ---------------------------------------------------------------------------
// Kernel 0c: transpose weights.  W[k][n] fp32 -> WT[n][k] fp16.
// ---------------------------------------------------------------------------
__global__ __launch_bounds__(256) void wtr_kernel(
    const float* __restrict__ Wq, const float* __restrict__ Wk,
    const float* __restrict__ Wv, const float* __restrict__ Wo,
    f16* __restrict__ WqT, f16* __restrict__ WkT,
    f16* __restrict__ WvT, f16* __restrict__ WoT)
{
    __shared__ float s_t[64][65];
    const int zz = blockIdx.z;
    const float* __restrict__ W = (zz == 0) ? Wq : (zz == 1) ? Wk : (zz == 2) ? Wv : Wo;
    const int k0 = blockIdx.y * 64, n0 = blockIdx.x * 64;
    const int t = threadIdx.x;
    const int r = t >> 2, c0 = (t & 3) * 16;

#pragma unroll
    for (int j = 0; j < 4; ++j) {
        float4 v = *(const float4*)(W + (size_t)(k0 + r) * D_ + n0 + c0 + j * 4);
        s_t[r][c0 + j * 4 + 0] = v.x;
        s_t[r][c0 + j * 4 + 1] = v.y;
        s_t[r][c0 + j * 4 + 2] = v.z;
        s_t[r][c0 + j * 4 + 3] = v.w;
    }
    __syncthreads();

    const int n = t >> 2, kc = (t & 3) * 16;
    f16x8 h0, h1;
#pragma unroll
    for (int j = 0; j < 8; ++j) h0[j] = (f16)s_t[kc + j][n];
#pragma unroll
    for (int j = 0; j < 8; ++j) h1[j] = (f16)s_t[kc + 8 + j][n];
    f16* dh = (zz == 0) ? WqT : (zz == 1) ? WkT : (zz == 2) ? WvT : WoT;
    size_t o = (size_t)(n0 + n) * D_ + k0 + kc;
    *(f16x8*)(dh + o) = h0;
    *(f16x8*)(dh + o + 8) = h1;
}

// ---------------------------------------------------------------------------
// Kernel 1: 128x128 fp16 GEMM, BK=32, global_load_lds staging.
// z: 0=Q (fp16, *1/8)  1=K (fp16, row-major [bh][t][dh])
//    2=V (fp16, BLOCKED [bh][t/32][dh][t%32] -> contiguous 4KB kv-tiles)
//    3=O (fp32 out)
// ---------------------------------------------------------------------------
__global__ __launch_bounds__(256) void gemm_kernel(
    const f16* __restrict__ A, int zbase,
    const f16* __restrict__ BqT, const f16* __restrict__ BkT,
    const f16* __restrict__ BvT, const f16* __restrict__ BoT,
    const float* __restrict__ bq, const float* __restrict__ bk,
    const float* __restrict__ bv, const float* __restrict__ bo,
    f16* __restrict__ Q, f16* __restrict__ K,
    f16* __restrict__ Vt, float* __restrict__ outF)
{
    __shared__ f16 sA[128 * 32];
    __shared__ f16 sB[128 * 32];

    const int z = blockIdx.z + zbase;
    const f16* __restrict__ Bm = (z == 0) ? BqT : (z == 1) ? BkT : (z == 2) ? BvT : BoT;
    const float* __restrict__ bias = (z == 0) ? bq : (z == 1) ? bk : (z == 2) ? bv : bo;

    const int m0 = blockIdx.y * 128;
    const int n0 = blockIdx.x * 128;
    const int tid = threadIdx.x;
    const int w = tid >> 6, l = tid & 63;
    const int g = l >> 4, lr = l & 15;
    const int wm = w >> 1, wn = w & 1;

    const int srow = w * 32 + (l >> 2);
    const int skb  = (l & 3) * 8;

    f32x4 acc[4][4] = {};

    for (int k0 = 0; k0 < D_; k0 += 32) {
        __syncthreads();
#pragma unroll
        for (int i = 0; i < 2; ++i) {
            gload16(A  + (size_t)(m0 + srow + i * 16) * D_ + k0 + skb,
                    &sA[w * 1024 + i * 512]);
            gload16(Bm + (size_t)(n0 + srow + i * 16) * D_ + k0 + skb,
                    &sB[w * 1024 + i * 512]);
        }
        __syncthreads();

        f16x8 ah[4], bh[4];
#pragma unroll
        for (int f = 0; f < 4; ++f) {
            ah[f] = *(const f16x8*)&sA[(wm * 64 + f * 16 + lr) * 32 + g * 8];
            bh[f] = *(const f16x8*)&sB[(wn * 64 + f * 16 + lr) * 32 + g * 8];
        }
#pragma unroll
        for (int fm = 0; fm < 4; ++fm)
#pragma unroll
            for (int fn = 0; fn < 4; ++fn)
                acc[fm][fn] = mfma16f(ah[fm], bh[fn], acc[fm][fn]);
    }

    const float scale = (z == 0) ? 0.125f : 1.0f;
    float biasv[4];
#pragma unroll
    for (int f = 0; f < 4; ++f) biasv[f] = bias[n0 + wn * 64 + f * 16 + lr];

    if (z <= 1) {
        f16* Oq = (z == 0) ? Q : K;
#pragma unroll
        for (int fm = 0; fm < 4; ++fm)
#pragma unroll
            for (int fn = 0; fn < 4; ++fn)
#pragma unroll
                for (int j = 0; j < 4; ++j) {
                    int r = m0 + wm * 64 + fm * 16 + g * 4 + j;
                    int c = n0 + wn * 64 + fn * 16 + lr;
                    float v = (acc[fm][fn][j] + biasv[fn]) * scale;
                    int b = r >> 11, t = r & (T_ - 1);
                    int h = (c >> 6) & 15, d = c & 63;
                    Oq[((size_t)(b * H_ + h) * T_ + t) * DH_ + d] = (f16)v;
                }
    } else if (z == 2) {
#pragma unroll
        for (int fm = 0; fm < 4; ++fm)
#pragma unroll
            for (int fn = 0; fn < 4; ++fn) {
                int r0 = m0 + wm * 64 + fm * 16 + g * 4;
                int c  = n0 + wn * 64 + fn * 16 + lr;
                int b = r0 >> 11, t0 = r0 & (T_ - 1);
                int h = (c >> 6) & 15, d = c & 63;
                union { f16 h4[4]; uint2 u; } pk;
#pragma unroll
                for (int j = 0; j < 4; ++j)
                    pk.h4[j] = (f16)(acc[fm][fn][j] + biasv[fn]);
                // blocked: [bh][t/32][dh][t%32]; 4 consecutive t stay in-tile
                *(uint2*)&Vt[(size_t)(b * H_ + h) * (T_ * DH_) +
                             (size_t)(t0 >> 5) * (32 * DH_) + d * 32 + (t0 & 31)] = pk.u;
            }
    } else {
#pragma unroll
        for (int fm = 0; fm < 4; ++fm)
#pragma unroll
            for (int fn = 0; fn < 4; ++fn)
#pragma unroll
                for (int j = 0; j < 4; ++j) {
                    int r = m0 + wm * 64 + fm * 16 + g * 4 + j;
                    int c = n0 + wn * 64 + fn * 16 + lr;
                    outF[(size_t)r * D_ + c] = acc[fm][fn][j] + biasv[fn];
                }
    }
}

// ---------------------------------------------------------------------------
// Kernel 2: flash attention.  vs R12: K/V tiles cooperatively staged into LDS
// (coalesced global_load_lds, double-buffered, shared by all 4 waves) instead
// of per-wave 32-line gathers; XOR-swizzled (source-side pre-swizzle, rule
// #21) so fragment ds_reads hit the 4-clock structural minimum; mask reads
// coalesced via transposed bitsT.  Softmax math identical to R12 (passing).
// ---------------------------------------------------------------------------
__device__ __forceinline__ void attn_tile(
    const f16x8* kh, const f16x8* vb, uint32_t mw, const f16x8* qf,
    f32x16& o0, f32x16& o1, float& m_run, float& l_run)
{
    const float L2E = 1.4426950408889634f;
    f32x16 s = {};
    __builtin_amdgcn_s_setprio(1);
    s = mfma32f(kh[0], qf[0], s);
    s = mfma32f(kh[1], qf[1], s);
    s = mfma32f(kh[2], qf[2], s);
    s = mfma32f(kh[3], qf[3], s);
    __builtin_amdgcn_s_setprio(0);

#pragma unroll
    for (int r = 0; r < 16; ++r) {
        const int bit = (r & 3) + 8 * (r >> 2);
        if (!((mw >> bit) & 1u)) s[r] = -1e30f;
    }

    float t8[8], t4[4];
#pragma unroll
    for (int i = 0; i < 8; ++i) t8[i] = fmaxf(s[i], s[i + 8]);
#pragma unroll
    for (int i = 0; i < 4; ++i) t4[i] = fmaxf(t8[i], t8[i + 4]);
    float pm = fmaxf(fmaxf(t4[0], t4[2]), fmaxf(t4[1], t4[3]));
    pm = xmax32(pm);

    if (__any(pm > m_run + 8.0f)) {        // defer-max rescale (T13)
        float mn  = fmaxf(m_run, pm);
        float fac = exp2f((m_run - mn) * L2E);
        l_run *= fac;
#pragma unroll
        for (int r = 0; r < 16; ++r) { o0[r] *= fac; o1[r] *= fac; }
        m_run = mn;
    }

    float p[16];
#pragma unroll
    for (int r = 0; r < 16; ++r) p[r] = exp2f((s[r] - m_run) * L2E);
    float a8[8], a4[4];
#pragma unroll
    for (int i = 0; i < 8; ++i) a8[i] = p[i] + p[i + 8];
#pragma unroll
    for (int i = 0; i < 4; ++i) a4[i] = a8[i] + a8[i + 4];
    float sum = (a4[0] + a4[2]) + (a4[1] + a4[3]);
    sum = xsum32(sum);
    l_run += sum;

    uint32_t wv[8];
#pragma unroll
    for (int m2 = 0; m2 < 8; ++m2) {
        union { fp16x2 h; uint32_t u; } cv;
        cv.h = __builtin_amdgcn_cvt_pkrtz(p[2 * m2], p[2 * m2 + 1]);
        wv[m2] = cv.u;
    }
    asm("v_permlane32_swap_b32 %0, %1" : "+v"(wv[0]), "+v"(wv[2]));
    asm("v_permlane32_swap_b32 %0, %1" : "+v"(wv[1]), "+v"(wv[3]));
    asm("v_permlane32_swap_b32 %0, %1" : "+v"(wv[4]), "+v"(wv[6]));
    asm("v_permlane32_swap_b32 %0, %1" : "+v"(wv[5]), "+v"(wv[7]));
    union { uint32_t u[4]; f16x8 s8; } pa1, pa2;
    pa1.u[0] = wv[0]; pa1.u[1] = wv[1]; pa1.u[2] = wv[2]; pa1.u[3] = wv[3];
    pa2.u[0] = wv[4]; pa2.u[1] = wv[5]; pa2.u[2] = wv[6]; pa2.u[3] = wv[7];

    __builtin_amdgcn_s_setprio(1);
    o0 = mfma32f(vb[0], pa1.s8, o0);
    o0 = mfma32f(vb[1], pa2.s8, o0);
    o1 = mfma32f(vb[2], pa1.s8, o1);
    o1 = mfma32f(vb[3], pa2.s8, o1);
    __builtin_amdgcn_s_setprio(0);
}

__global__ __launch_bounds__(256, 3) void attn_split_kernel(
    const f16* __restrict__ Qg, const f16* __restrict__ Kg,
    const f16* __restrict__ Vt, const uint32_t* __restrict__ bits,
    f16* __restrict__ Op0, f16* __restrict__ Op1,
    float2* __restrict__ stats)
{
    __shared__ f16 sK[2][2048];   // [32 kv rows][64 dh] fp16, 4KB per buf
    __shared__ f16 sV[2][2048];   // [64 dh rows][32 kv] fp16, 4KB per buf

    const int bx  = blockIdx.x;
    const int bh  = (bx & 7) | ((bx >> 8) << 3);
    const int mid = (bx >> 3) & 31;
    const int qb  = mid >> 1;
    const int sp  = mid & 1;
    const int b   = bh >> 4, h = bh & 15;
    const int tid = threadIdx.x;
    const int w   = tid >> 6;
    const int l   = tid & 63;
    const int qi  = l & 31;
    const int hl  = l >> 5;
    const int q   = qb * 128 + w * 32 + qi;
    const int kvbase = sp * KVSPAN;

    const size_t hoff = (size_t)(b * H_ + h) * T_ * DH_;
    const f16* Qh = Qg + hoff;
    const f16* Kh = Kg + hoff;                 // [t][dh]
    const f16* Vh = Vt + hoff;                 // blocked [t/32][dh][t%32]
    // transposed mask: bitsT[b][word][q]; per-lane q -> coalesced
    const uint32_t* mbase = bits + (size_t)b * (64 * T_) + q;

    // staging source offsets (pre-swizzled so linear LDS + swizzled reads
    // are conflict-minimal; involution on 16B chunks)
    const int krow = tid >> 3, kch = tid & 7;              // K: 32 rows x 8 chunks
    const size_t ksoff = (size_t)krow * DH_ + (size_t)((kch ^ (krow & 7)) * 8);
    const int vrow = tid >> 2, vch = tid & 3;              // V: 64 rows x 4 chunks
    const size_t vsoff = (size_t)vrow * 32 + (size_t)((vch ^ ((vrow >> 1) & 3)) * 8);

    f16x8 qf[4];
#pragma unroll
    for (int c = 0; c < 4; ++c)
        qf[c] = *(const f16x8*)&Qh[(size_t)q * DH_ + c * 16 + hl * 8];

    f32x16 o0 = {}; f32x16 o1 = {};
    float m_run = -1e30f, l_run = 0.0f;

#define STAGE(buf, kv)                                                        \
    do {                                                                      \
        gload16(Kh + (size_t)(kv) * DH_ + ksoff, &sK[buf][w * 512]);          \
        gload16(Vh + (size_t)((kv) >> 5) * 2048 + vsoff, &sV[buf][w * 512]);  \
    } while (0)

    STAGE(0, kvbase);
    __syncthreads();

    int cur = 0;
    for (int kv0 = kvbase; kv0 < kvbase + KVSPAN; kv0 += 32) {
        int nxt = kv0 + 32;
        if (nxt == kvbase + KVSPAN) nxt = kvbase;   // harmless wrap refill
        STAGE(cur ^ 1, nxt);

        uint32_t mw = mbase[(size_t)(kv0 >> 5) * T_] >> (hl * 4);

        f16x8 kh[4], vb[4];
#pragma unroll
        for (int c = 0; c < 4; ++c)
            kh[c] = *(const f16x8*)&sK[cur][qi * DH_ + (((2 * c + hl) ^ (qi & 7)) << 3)];
#pragma unroll
        for (int j = 0; j < 4; ++j) {
            int row = (j >> 1) * 32 + qi;
            int ch  = ((j & 1) * 2 + hl) ^ ((qi >> 1) & 3);
            vb[j] = *(const f16x8*)&sV[cur][row * 32 + (ch << 3)];
        }

        attn_tile(kh, vb, mw, qf, o0, o1, m_run, l_run);
        __syncthreads();   // drains this tile's prefetch; syncs buffer swap
        cur ^= 1;
    }
#undef STAGE

    // epilogue: normalized partial O -> Op[sp], stats (m,l) -> stats[sp]
    float inv = 1.0f / l_run;
    float ov[32];
#pragma unroll
    for (int r = 0; r < 16; ++r) { ov[r] = o0[r]; ov[16 + r] = o1[r]; }
    f16* Op = (sp == 0) ? Op0 : Op1;
    f16* prow = Op + ((size_t)bh * T_ + q) * DH_;
#pragma unroll
    for (int dt = 0; dt < 2; ++dt)
#pragma unroll
        for (int g2 = 0; g2 < 4; ++g2) {
            union { f16 h4[4]; uint2 u; } pk;
#pragma unroll
            for (int j = 0; j < 4; ++j)
                pk.h4[j] = (f16)(ov[dt * 16 + 4 * g2 + j] * inv);
            *(uint2*)(prow + dt * 32 + 8 * g2 + 4 * hl) = pk.u;
        }
    if (hl == 0)
        stats[(size_t)sp * (32 * T_) + (size_t)bh * T_ + q] =
            make_float2(m_run, l_run);
}

// ---------------------------------------------------------------------------
// Kernel 2b: combine the two KV-split partials -> comb (fp16 [B,T,D]).
// ---------------------------------------------------------------------------
__global__ __launch_bounds__(256) void combine_kernel(
    const f16* __restrict__ Op0, const f16* __restrict__ Op1,
    const float2* __restrict__ stats, f16* __restrict__ comb)
{
    const float L2E = 1.4426950408889634f;
    const int row = blockIdx.x * 32 + (threadIdx.x >> 3);   // [0, 32*T_)
    const int dh0 = (threadIdx.x & 7) * 8;
    const int bh = row >> 11, q = row & (T_ - 1);
    const int b = bh >> 4, h = bh & 15;

    float2 s0 = stats[row];
    float2 s1 = stats[32 * T_ + row];
    float m = fmaxf(s0.x, s1.x);
    float w0 = s0.y * exp2f((s0.x - m) * L2E);
    float w1 = s1.y * exp2f((s1.x - m) * L2E);
    float rs = 1.0f / (w0 + w1);
    float a0 = w0 * rs, a1 = w1 * rs;

    f16x8 v0 = *(const f16x8*)(Op0 + (size_t)row * DH_ + dh0);
    f16x8 v1 = *(const f16x8*)(Op1 + (size_t)row * DH_ + dh0);
    f16x8 ou;
#pragma unroll
    for (int i = 0; i < 8; ++i)
        ou[i] = (f16)(a0 * (float)v0[i] + a1 * (float)v1[i]);
    *(f16x8*)(comb + ((size_t)(b * T_ + q)) * D_ + h * DH_ + dh0) = ou;
}

// ---------------------------------------------------------------------------
extern "C" void kernel_launch(void* const* d_in, const int* in_sizes, int n_in,
                              void* d_out, int out_size, void* d_ws, size_t ws_size,
                              hipStream_t stream)
{
    const float* X    = (const float*)d_in[0];
    const int*   mask = (const int*)d_in[1];
    const float* Wq   = (const float*)d_in[2];
    const float* bq   = (const float*)d_in[3];
    const float* Wk   = (const float*)d_in[4];
    const float* bk   = (const float*)d_in[5];
    const float* Wv   = (const float*)d_in[6];
    const float* bv   = (const float*)d_in[7];
    const float* Wo   = (const float*)d_in[8];
    const float* bo   = (const float*)d_in[9];
    float* out = (float*)d_out;

    const size_t SEG  = (size_t)B_ * T_ * D_;   // 4,194,304 elems (8 MiB fp16)
    const size_t WSEG = (size_t)D_ * D_;        // 2 MiB fp16
    f16* wsp = (f16*)d_ws;
    f16* Q    = wsp + 0 * SEG;
    f16* K    = wsp + 1 * SEG;
    f16* Xh   = wsp + 2 * SEG;     // comb aliases Xh after QKV GEMM
    f16* Op0  = wsp + 3 * SEG;
    f16* WqT  = wsp + 4 * SEG;
    f16* WkT  = WqT + 1 * WSEG;
    f16* WvT  = WqT + 2 * WSEG;
    f16* WoT  = WqT + 3 * WSEG;
    f16* Op1  = wsp + 5 * SEG;     // ws total: 48 MiB
    f16* comb = Xh;
    // d_out scratch: Vt (8 MiB) + bitsT (1 MiB) + stats (1 MiB); final GEMM
    // overwrites all of d_out.
    f16* Vt = (f16*)d_out;
    uint32_t* bits = (uint32_t*)((char*)d_out + (8u << 20));
    float2* stats  = (float2*)((char*)d_out + (9u << 20));

    dim3 blk(256);
    maskpack_kernel<<<dim3((B_ * T_ * T_) / 256), blk, 0, stream>>>(mask, bits);
    cvtx_kernel<<<dim3((B_ * T_ * D_) / 2048), blk, 0, stream>>>(X, Xh);
    wtr_kernel<<<dim3(16, 16, 4), blk, 0, stream>>>(
        Wq, Wk, Wv, Wo, WqT, WkT, WvT, WoT);
    gemm_kernel<<<dim3(D_ / 128, (B_ * T_) / 128, 3), blk, 0, stream>>>(
        Xh, 0, WqT, WkT, WvT, WoT,
        bq, bk, bv, bo, Q, K, Vt, out);
    attn_split_kernel<<<dim3(B_ * H_ * (T_ / 128) * NSPLIT), blk, 0, stream>>>(
        Q, K, Vt, bits, Op0, Op1, stats);
    combine_kernel<<<dim3((32 * T_) / 32), blk, 0, stream>>>(
        Op0, Op1, stats, comb);
    gemm_kernel<<<dim3(D_ / 128, (B_ * T_) / 128, 1), blk, 0, stream>>>(
        comb, 3, WqT, WkT, WvT, WoT,
        bq, bk, bv, bo, Q, K, Vt, out);
}

// Round 15
// 161.181 us; speedup vs baseline: 3.6321x; 1.0034x over previous
//
#include <hip/hip_runtime.h>
#include <hip/hip_bf16.h>
#include <stdint.h>

typedef _Float16 f16;
typedef __attribute__((ext_vector_type(8))) _Float16 f16x8;
typedef __attribute__((ext_vector_type(2))) __fp16 fp16x2;
typedef __attribute__((ext_vector_type(4))) float f32x4;
typedef __attribute__((ext_vector_type(16))) float f32x16;

#define B_  2
#define T_  2048
#define D_  1024
#define H_  16
#define DH_ 64
#define NSPLIT 2
#define KVSPAN (T_ / NSPLIT)

__device__ __forceinline__ f32x4 mfma16f(f16x8 a, f16x8 b, f32x4 c) {
    return __builtin_amdgcn_mfma_f32_16x16x32_f16(a, b, c, 0, 0, 0);
}
__device__ __forceinline__ f32x16 mfma32f(f16x8 a, f16x8 b, f32x16 c) {
    return __builtin_amdgcn_mfma_f32_32x32x16_f16(a, b, c, 0, 0, 0);
}
__device__ __forceinline__ void gload16(const void* g, void* l) {
    __builtin_amdgcn_global_load_lds(
        (const __attribute__((address_space(1))) uint32_t*)g,
        (__attribute__((address_space(3))) uint32_t*)l, 16, 0, 0);
}
// cross-half (lane ^ 32) max/sum via v_permlane32_swap (hazard-safe, R12).
__device__ __forceinline__ float xmax32(float x) {
    float a, b;
    asm("v_mov_b32 %0, %2\n\t"
        "v_mov_b32 %1, %2\n\t"
        "s_nop 1\n\t"
        "v_permlane32_swap_b32 %0, %1\n\t"
        "s_nop 1\n\t"
        "v_max_f32 %0, %0, %1"
        : "=&v"(a), "=&v"(b) : "v"(x));
    return a;
}
__device__ __forceinline__ float xsum32(float x) {
    float a, b;
    asm("v_mov_b32 %0, %2\n\t"
        "v_mov_b32 %1, %2\n\t"
        "s_nop 1\n\t"
        "v_permlane32_swap_b32 %0, %1\n\t"
        "s_nop 1\n\t"
        "v_add_f32 %0, %0, %1"
        : "=&v"(a), "=&v"(b) : "v"(x));
    return a;
}
__device__ __forceinline__ float max3f(float a, float b, float c) {
    return fmaxf(fmaxf(a, b), c);   // fuses to v_max3_f32
}

// ---------------------------------------------------------------------------
// Kernel 0: pack int32 mask -> TRANSPOSED bit mask bitsT[b][word][q].
// ---------------------------------------------------------------------------
__global__ __launch_bounds__(256) void maskpack_kernel(
    const int* __restrict__ mask, uint32_t* __restrict__ bitsT)
{
    size_t e = (size_t)blockIdx.x * 256 + threadIdx.x;   // [B][T][T] linear
    unsigned long long bb = __ballot(mask[e] != 0);
    if ((threadIdx.x & 63) == 0) {
        size_t r = e >> 11;              // b*T + q
        int b = (int)(r >> 11), q = (int)(r & (T_ - 1));
        int k = (int)(e & (T_ - 1));
        int w0 = k >> 5;
        size_t base = (size_t)b * (64 * T_) + q;
        bitsT[base + (size_t)w0 * T_]       = (uint32_t)bb;
        bitsT[base + (size_t)(w0 + 1) * T_] = (uint32_t)(bb >> 32);
    }
}

// ---------------------------------------------------------------------------
// Kernel 0b: convert X fp32 -> fp16.
// ---------------------------------------------------------------------------
__global__ __launch_bounds__(256) void cvtx_kernel(
    const float* __restrict__ X, f16* __restrict__ Xh)
{
    size_t i0 = ((size_t)blockIdx.x * 256 + threadIdx.x) * 8;
    float4 a = *(const float4*)(X + i0);
    float4 b = *(const float4*)(X + i0 + 4);
    float v[8] = {a.x, a.y, a.z, a.w, b.x, b.y, b.z, b.w};
    f16x8 hh;
#pragma unroll
    for (int i = 0; i < 8; ++i) hh[i] = (f16)v[i];
    *(f16x8*)(Xh + i0) = hh;
}

// ---------------------------------------------------------------------------
// Kernel 0c: transpose weights.  W[k][n] fp32 -> WT[n][k] fp16.
// ---------------------------------------------------------------------------
__global__ __launch_bounds__(256) void wtr_kernel(
    const float* __restrict__ Wq, const float* __restrict__ Wk,
    const float* __restrict__ Wv, const float* __restrict__ Wo,
    f16* __restrict__ WqT, f16* __restrict__ WkT,
    f16* __restrict__ WvT, f16* __restrict__ WoT)
{
    __shared__ float s_t[64][65];
    const int zz = blockIdx.z;
    const float* __restrict__ W = (zz == 0) ? Wq : (zz == 1) ? Wk : (zz == 2) ? Wv : Wo;
    const int k0 = blockIdx.y * 64, n0 = blockIdx.x * 64;
    const int t = threadIdx.x;
    const int r = t >> 2, c0 = (t & 3) * 16;

#pragma unroll
    for (int j = 0; j < 4; ++j) {
        float4 v = *(const float4*)(W + (size_t)(k0 + r) * D_ + n0 + c0 + j * 4);
        s_t[r][c0 + j * 4 + 0] = v.x;
        s_t[r][c0 + j * 4 + 1] = v.y;
        s_t[r][c0 + j * 4 + 2] = v.z;
        s_t[r][c0 + j * 4 + 3] = v.w;
    }
    __syncthreads();

    const int n = t >> 2, kc = (t & 3) * 16;
    f16x8 h0, h1;
#pragma unroll
    for (int j = 0; j < 8; ++j) h0[j] = (f16)s_t[kc + j][n];
#pragma unroll
    for (int j = 0; j < 8; ++j) h1[j] = (f16)s_t[kc + 8 + j][n];
    f16* dh = (zz == 0) ? WqT : (zz == 1) ? WkT : (zz == 2) ? WvT : WoT;
    size_t o = (size_t)(n0 + n) * D_ + k0 + kc;
    *(f16x8*)(dh + o) = h0;
    *(f16x8*)(dh + o + 8) = h1;
}

// ---------------------------------------------------------------------------
// Kernel 1: 128x128 fp16 GEMM (QKV), BK=32, global_load_lds staging.
// z: 0=Q (fp16, *1/8)  1=K (fp16, [bh][t][dh])
//    2=V (fp16, BLOCKED [bh][t/32][dh][t%32])
// ---------------------------------------------------------------------------
__global__ __launch_bounds__(256) void gemm_kernel(
    const f16* __restrict__ A,
    const f16* __restrict__ BqT, const f16* __restrict__ BkT,
    const f16* __restrict__ BvT,
    const float* __restrict__ bq, const float* __restrict__ bk,
    const float* __restrict__ bv,
    f16* __restrict__ Q, f16* __restrict__ K, f16* __restrict__ Vt)
{
    __shared__ f16 sA[128 * 32];
    __shared__ f16 sB[128 * 32];

    const int z = blockIdx.z;
    const f16* __restrict__ Bm = (z == 0) ? BqT : (z == 1) ? BkT : BvT;
    const float* __restrict__ bias = (z == 0) ? bq : (z == 1) ? bk : bv;

    const int m0 = blockIdx.y * 128;
    const int n0 = blockIdx.x * 128;
    const int tid = threadIdx.x;
    const int w = tid >> 6, l = tid & 63;
    const int g = l >> 4, lr = l & 15;
    const int wm = w >> 1, wn = w & 1;

    const int srow = w * 32 + (l >> 2);
    const int skb  = (l & 3) * 8;

    f32x4 acc[4][4] = {};

    for (int k0 = 0; k0 < D_; k0 += 32) {
        __syncthreads();
#pragma unroll
        for (int i = 0; i < 2; ++i) {
            gload16(A  + (size_t)(m0 + srow + i * 16) * D_ + k0 + skb,
                    &sA[w * 1024 + i * 512]);
            gload16(Bm + (size_t)(n0 + srow + i * 16) * D_ + k0 + skb,
                    &sB[w * 1024 + i * 512]);
        }
        __syncthreads();

        f16x8 ah[4], bh[4];
#pragma unroll
        for (int f = 0; f < 4; ++f) {
            ah[f] = *(const f16x8*)&sA[(wm * 64 + f * 16 + lr) * 32 + g * 8];
            bh[f] = *(const f16x8*)&sB[(wn * 64 + f * 16 + lr) * 32 + g * 8];
        }
#pragma unroll
        for (int fm = 0; fm < 4; ++fm)
#pragma unroll
            for (int fn = 0; fn < 4; ++fn)
                acc[fm][fn] = mfma16f(ah[fm], bh[fn], acc[fm][fn]);
    }

    const float scale = (z == 0) ? 0.125f : 1.0f;
    float biasv[4];
#pragma unroll
    for (int f = 0; f < 4; ++f) biasv[f] = bias[n0 + wn * 64 + f * 16 + lr];

    if (z <= 1) {
        f16* Oq = (z == 0) ? Q : K;
#pragma unroll
        for (int fm = 0; fm < 4; ++fm)
#pragma unroll
            for (int fn = 0; fn < 4; ++fn)
#pragma unroll
                for (int j = 0; j < 4; ++j) {
                    int r = m0 + wm * 64 + fm * 16 + g * 4 + j;
                    int c = n0 + wn * 64 + fn * 16 + lr;
                    float v = (acc[fm][fn][j] + biasv[fn]) * scale;
                    int b = r >> 11, t = r & (T_ - 1);
                    int h = (c >> 6) & 15, d = c & 63;
                    Oq[((size_t)(b * H_ + h) * T_ + t) * DH_ + d] = (f16)v;
                }
    } else {
#pragma unroll
        for (int fm = 0; fm < 4; ++fm)
#pragma unroll
            for (int fn = 0; fn < 4; ++fn) {
                int r0 = m0 + wm * 64 + fm * 16 + g * 4;
                int c  = n0 + wn * 64 + fn * 16 + lr;
                int b = r0 >> 11, t0 = r0 & (T_ - 1);
                int h = (c >> 6) & 15, d = c & 63;
                union { f16 h4[4]; uint2 u; } pk;
#pragma unroll
                for (int j = 0; j < 4; ++j)
                    pk.h4[j] = (f16)(acc[fm][fn][j] + biasv[fn]);
                *(uint2*)&Vt[(size_t)(b * H_ + h) * (T_ * DH_) +
                             (size_t)(t0 >> 5) * (32 * DH_) + d * 32 + (t0 & 31)] = pk.u;
            }
    }
}

// ---------------------------------------------------------------------------
// Kernel 1b: O-projection GEMM, BM=128 x BN=64 (512 blocks -> 2 waves/SIMD).
// out(fp32) = comb(fp16) @ WoT^T + bo.
// ---------------------------------------------------------------------------
__global__ __launch_bounds__(256) void oproj_kernel(
    const f16* __restrict__ A, const f16* __restrict__ BoT,
    const float* __restrict__ bo, float* __restrict__ outF)
{
    __shared__ f16 sA[128 * 32];
    __shared__ f16 sB[64 * 32];

    const int m0 = blockIdx.y * 128;
    const int n0 = blockIdx.x * 64;
    const int tid = threadIdx.x;
    const int w = tid >> 6, l = tid & 63;
    const int g = l >> 4, lr = l & 15;

    const int srowA = w * 32 + (l >> 2);
    const int skbA  = (l & 3) * 8;
    const int browB = w * 16 + (l >> 2);

    f32x4 acc[2][4] = {};

    for (int k0 = 0; k0 < D_; k0 += 32) {
        __syncthreads();
#pragma unroll
        for (int i = 0; i < 2; ++i)
            gload16(A + (size_t)(m0 + srowA + i * 16) * D_ + k0 + skbA,
                    &sA[w * 1024 + i * 512]);
        gload16(BoT + (size_t)(n0 + browB) * D_ + k0 + skbA,
                &sB[w * 512]);
        __syncthreads();

        f16x8 ah[2], bh[4];
#pragma unroll
        for (int f = 0; f < 2; ++f)
            ah[f] = *(const f16x8*)&sA[(w * 32 + f * 16 + lr) * 32 + g * 8];
#pragma unroll
        for (int f = 0; f < 4; ++f)
            bh[f] = *(const f16x8*)&sB[(f * 16 + lr) * 32 + g * 8];
#pragma unroll
        for (int fm = 0; fm < 2; ++fm)
#pragma unroll
            for (int fn = 0; fn < 4; ++fn)
                acc[fm][fn] = mfma16f(ah[fm], bh[fn], acc[fm][fn]);
    }

    float biasv[4];
#pragma unroll
    for (int f = 0; f < 4; ++f) biasv[f] = bo[n0 + f * 16 + lr];
#pragma unroll
    for (int fm = 0; fm < 2; ++fm)
#pragma unroll
        for (int fn = 0; fn < 4; ++fn)
#pragma unroll
            for (int j = 0; j < 4; ++j) {
                int r = m0 + w * 32 + fm * 16 + g * 4 + j;
                int c = n0 + fn * 16 + lr;
                outF[(size_t)r * D_ + c] = acc[fm][fn][j] + biasv[fn];
            }
}

// ---------------------------------------------------------------------------
// Kernel 2: flash attention.  vs R13: KVBLK=64 (half the barriers/fixed cost),
// max3-fused tree, row-sum via v_dot2_f32_f16 on masked packed P.
// Mask semantics unchanged (mask -> s BEFORE max, R12-proven).
// ---------------------------------------------------------------------------
__device__ __forceinline__ void attn_tile(
    const f16x8* kh, const f16x8* vb, uint32_t mw, const f16x8* qf,
    f32x16& o0, f32x16& o1, float& m_run, float& l_run)
{
    const float L2E = 1.4426950408889634f;
    f32x16 s = {};
    __builtin_amdgcn_s_setprio(1);
    s = mfma32f(kh[0], qf[0], s);
    s = mfma32f(kh[1], qf[1], s);
    s = mfma32f(kh[2], qf[2], s);
    s = mfma32f(kh[3], qf[3], s);
    __builtin_amdgcn_s_setprio(0);

#pragma unroll
    for (int r = 0; r < 16; ++r) {
        const int bit = (r & 3) + 8 * (r >> 2);
        if (!((mw >> bit) & 1u)) s[r] = -1e30f;
    }

    // row-max: max3-fused tree (16 -> 6 -> 2 -> 1), then cross-half permlane
    float u0 = max3f(s[0],  s[1],  s[2]);
    float u1 = max3f(s[3],  s[4],  s[5]);
    float u2 = max3f(s[6],  s[7],  s[8]);
    float u3 = max3f(s[9],  s[10], s[11]);
    float u4 = max3f(s[12], s[13], s[14]);
    float pm = fmaxf(max3f(u0, u1, u2), max3f(u3, u4, s[15]));
    pm = xmax32(pm);

    if (__any(pm > m_run + 8.0f)) {        // defer-max rescale (T13)
        float mn  = fmaxf(m_run, pm);
        float fac = exp2f((m_run - mn) * L2E);
        l_run *= fac;
#pragma unroll
        for (int r = 0; r < 16; ++r) { o0[r] *= fac; o1[r] *= fac; }
        m_run = mn;
    }

    float p[16];
#pragma unroll
    for (int r = 0; r < 16; ++r) p[r] = exp2f((s[r] - m_run) * L2E);

    uint32_t wv[8];
#pragma unroll
    for (int m2 = 0; m2 < 8; ++m2) {
        union { fp16x2 h; uint32_t u; } cv;
        cv.h = __builtin_amdgcn_cvt_pkrtz(p[2 * m2], p[2 * m2 + 1]);
        wv[m2] = cv.u;
    }

    // row-sum from the packed (masked-consistent) P
#if __has_builtin(__builtin_amdgcn_fdot2)
    fp16x2 onep; onep[0] = (__fp16)1.0f; onep[1] = (__fp16)1.0f;
    float sA_ = 0.0f, sB_ = 0.0f;
#pragma unroll
    for (int m2 = 0; m2 < 8; m2 += 2) {
        union { uint32_t u; fp16x2 h; } ca, cb;
        ca.u = wv[m2]; cb.u = wv[m2 + 1];
        sA_ = __builtin_amdgcn_fdot2(ca.h, onep, sA_, false);
        sB_ = __builtin_amdgcn_fdot2(cb.h, onep, sB_, false);
    }
    float sum = sA_ + sB_;
#else
    float a8[8], a4[4];
#pragma unroll
    for (int i = 0; i < 8; ++i) a8[i] = p[i] + p[i + 8];
#pragma unroll
    for (int i = 0; i < 4; ++i) a4[i] = a8[i] + a8[i + 4];
    float sum = (a4[0] + a4[2]) + (a4[1] + a4[3]);
#endif
    sum = xsum32(sum);
    l_run += sum;

    asm("v_permlane32_swap_b32 %0, %1" : "+v"(wv[0]), "+v"(wv[2]));
    asm("v_permlane32_swap_b32 %0, %1" : "+v"(wv[1]), "+v"(wv[3]));
    asm("v_permlane32_swap_b32 %0, %1" : "+v"(wv[4]), "+v"(wv[6]));
    asm("v_permlane32_swap_b32 %0, %1" : "+v"(wv[5]), "+v"(wv[7]));
    union { uint32_t u[4]; f16x8 s8; } pa1, pa2;
    pa1.u[0] = wv[0]; pa1.u[1] = wv[1]; pa1.u[2] = wv[2]; pa1.u[3] = wv[3];
    pa2.u[0] = wv[4]; pa2.u[1] = wv[5]; pa2.u[2] = wv[6]; pa2.u[3] = wv[7];

    __builtin_amdgcn_s_setprio(1);
    o0 = mfma32f(vb[0], pa1.s8, o0);
    o0 = mfma32f(vb[1], pa2.s8, o0);
    o1 = mfma32f(vb[2], pa1.s8, o1);
    o1 = mfma32f(vb[3], pa2.s8, o1);
    __builtin_amdgcn_s_setprio(0);
}

__global__ __launch_bounds__(256, 3) void attn_split_kernel(
    const f16* __restrict__ Qg, const f16* __restrict__ Kg,
    const f16* __restrict__ Vt, const uint32_t* __restrict__ bits,
    f16* __restrict__ Op0, f16* __restrict__ Op1,
    float2* __restrict__ stats)
{
    __shared__ f16 sK[2][64 * 64];       // [64 kv rows][64 dh], 8KB per buf
    __shared__ f16 sV[2][2][64 * 32];    // [2 kv-blocks][64 dh][32 kv], 8KB/buf

    const int bx  = blockIdx.x;
    const int bh  = (bx & 7) | ((bx >> 8) << 3);
    const int mid = (bx >> 3) & 31;
    const int qb  = mid >> 1;
    const int sp  = mid & 1;
    const int b   = bh >> 4, h = bh & 15;
    const int tid = threadIdx.x;
    const int w   = tid >> 6;
    const int l   = tid & 63;
    const int qi  = l & 31;
    const int hl  = l >> 5;
    const int q   = qb * 128 + w * 32 + qi;
    const int kvbase = sp * KVSPAN;

    const size_t hoff = (size_t)(b * H_ + h) * T_ * DH_;
    const f16* Qh = Qg + hoff;
    const f16* Kh = Kg + hoff;                 // [t][dh]
    const f16* Vh = Vt + hoff;                 // blocked [t/32][dh][t%32]
    const uint32_t* mbase = bits + (size_t)b * (64 * T_) + q;

    // staging source offsets (pre-swizzled; involution on 16B chunks)
    const int krow8 = l >> 3, kch = l & 7;     // 8 rows x 8 chunks per gload
    const int vrow16 = l >> 2, vch = l & 3;    // 16 rows x 4 chunks per gload

    f16x8 qf[4];
#pragma unroll
    for (int c = 0; c < 4; ++c)
        qf[c] = *(const f16x8*)&Qh[(size_t)q * DH_ + c * 16 + hl * 8];

    f32x16 o0 = {}; f32x16 o1 = {};
    float m_run = -1e30f, l_run = 0.0f;

    // K: 64 rows; wave w site s covers rows s*32 + w*8 .. +7
    // V: 2 blocks of [64 dh][32 kv]; wave w covers dh rows w*16..+15 per block
#define STAGE(buf, kv)                                                         \
    do {                                                                       \
        _Pragma("unroll")                                                      \
        for (int si = 0; si < 2; ++si) {                                       \
            int krow = si * 32 + w * 8 + krow8;                                \
            gload16(Kh + (size_t)((kv) + krow) * DH_ +                         \
                        ((kch ^ (krow & 7)) * 8),                              \
                    &sK[buf][(size_t)(si * 32 + w * 8) * 64]);                 \
            int vrow = w * 16 + vrow16;                                        \
            gload16(Vh + (size_t)(((kv) >> 5) + si) * 2048 + vrow * 32 +       \
                        ((vch ^ ((vrow >> 1) & 3)) * 8),                       \
                    &sV[buf][si][(size_t)(w * 16) * 32]);                      \
        }                                                                      \
    } while (0)

    STAGE(0, kvbase);
    __syncthreads();

    int cur = 0;
    for (int kv0 = kvbase; kv0 < kvbase + KVSPAN; kv0 += 64) {
        int nxt = kv0 + 64;
        if (nxt == kvbase + KVSPAN) nxt = kvbase;   // harmless wrap refill
        STAGE(cur ^ 1, nxt);

        uint32_t mw0 = mbase[(size_t)(kv0 >> 5) * T_] >> (hl * 4);
        uint32_t mw1 = mbase[(size_t)((kv0 >> 5) + 1) * T_] >> (hl * 4);

#pragma unroll
        for (int half = 0; half < 2; ++half) {
            f16x8 kh[4], vb[4];
            const int row = qi + 32 * half;
#pragma unroll
            for (int c = 0; c < 4; ++c)
                kh[c] = *(const f16x8*)&sK[cur][row * 64 +
                            (((2 * c + hl) ^ (row & 7)) << 3)];
#pragma unroll
            for (int j = 0; j < 4; ++j) {
                int vrow = (j >> 1) * 32 + qi;
                int ch  = ((j & 1) * 2 + hl) ^ ((qi >> 1) & 3);
                vb[j] = *(const f16x8*)&sV[cur][half][vrow * 32 + (ch << 3)];
            }
            attn_tile(kh, vb, half ? mw1 : mw0, qf, o0, o1, m_run, l_run);
        }

        __syncthreads();   // drains prefetch; syncs buffer swap
        cur ^= 1;
    }
#undef STAGE

    // epilogue: normalized partial O -> Op[sp], stats (m,l) -> stats[sp]
    float inv = 1.0f / l_run;
    float ov[32];
#pragma unroll
    for (int r = 0; r < 16; ++r) { ov[r] = o0[r]; ov[16 + r] = o1[r]; }
    f16* Op = (sp == 0) ? Op0 : Op1;
    f16* prow = Op + ((size_t)bh * T_ + q) * DH_;
#pragma unroll
    for (int dt = 0; dt < 2; ++dt)
#pragma unroll
        for (int g2 = 0; g2 < 4; ++g2) {
            union { f16 h4[4]; uint2 u; } pk;
#pragma unroll
            for (int j = 0; j < 4; ++j)
                pk.h4[j] = (f16)(ov[dt * 16 + 4 * g2 + j] * inv);
            *(uint2*)(prow + dt * 32 + 8 * g2 + 4 * hl) = pk.u;
        }
    if (hl == 0)
        stats[(size_t)sp * (32 * T_) + (size_t)bh * T_ + q] =
            make_float2(m_run, l_run);
}

// ---------------------------------------------------------------------------
// Kernel 2b: combine the two KV-split partials -> comb (fp16 [B,T,D]).
// ---------------------------------------------------------------------------
__global__ __launch_bounds__(256) void combine_kernel(
    const f16* __restrict__ Op0, const f16* __restrict__ Op1,
    const float2* __restrict__ stats, f16* __restrict__ comb)
{
    const float L2E = 1.4426950408889634f;
    const int row = blockIdx.x * 32 + (threadIdx.x >> 3);   // [0, 32*T_)
    const int dh0 = (threadIdx.x & 7) * 8;
    const int bh = row >> 11, q = row & (T_ - 1);
    const int b = bh >> 4, h = bh & 15;

    float2 s0 = stats[row];
    float2 s1 = stats[32 * T_ + row];
    float m = fmaxf(s0.x, s1.x);
    float w0 = s0.y * exp2f((s0.x - m) * L2E);
    float w1 = s1.y * exp2f((s1.x - m) * L2E);
    float rs = 1.0f / (w0 + w1);
    float a0 = w0 * rs, a1 = w1 * rs;

    f16x8 v0 = *(const f16x8*)(Op0 + (size_t)row * DH_ + dh0);
    f16x8 v1 = *(const f16x8*)(Op1 + (size_t)row * DH_ + dh0);
    f16x8 ou;
#pragma unroll
    for (int i = 0; i < 8; ++i)
        ou[i] = (f16)(a0 * (float)v0[i] + a1 * (float)v1[i]);
    *(f16x8*)(comb + ((size_t)(b * T_ + q)) * D_ + h * DH_ + dh0) = ou;
}

// ---------------------------------------------------------------------------
extern "C" void kernel_launch(void* const* d_in, const int* in_sizes, int n_in,
                              void* d_out, int out_size, void* d_ws, size_t ws_size,
                              hipStream_t stream)
{
    const float* X    = (const float*)d_in[0];
    const int*   mask = (const int*)d_in[1];
    const float* Wq   = (const float*)d_in[2];
    const float* bq   = (const float*)d_in[3];
    const float* Wk   = (const float*)d_in[4];
    const float* bk   = (const float*)d_in[5];
    const float* Wv   = (const float*)d_in[6];
    const float* bv   = (const float*)d_in[7];
    const float* Wo   = (const float*)d_in[8];
    const float* bo   = (const float*)d_in[9];
    float* out = (float*)d_out;

    const size_t SEG  = (size_t)B_ * T_ * D_;   // 4,194,304 elems (8 MiB fp16)
    const size_t WSEG = (size_t)D_ * D_;        // 2 MiB fp16
    f16* wsp = (f16*)d_ws;
    f16* Q    = wsp + 0 * SEG;
    f16* K    = wsp + 1 * SEG;
    f16* Xh   = wsp + 2 * SEG;     // comb aliases Xh after QKV GEMM
    f16* Op0  = wsp + 3 * SEG;
    f16* WqT  = wsp + 4 * SEG;
    f16* WkT  = WqT + 1 * WSEG;
    f16* WvT  = WqT + 2 * WSEG;
    f16* WoT  = WqT + 3 * WSEG;
    f16* Op1  = wsp + 5 * SEG;     // ws total: 48 MiB
    f16* comb = Xh;
    // d_out scratch: Vt (8 MiB) + bitsT (1 MiB) + stats (1 MiB); oproj
    // overwrites all of d_out.
    f16* Vt = (f16*)d_out;
    uint32_t* bits = (uint32_t*)((char*)d_out + (8u << 20));
    float2* stats  = (float2*)((char*)d_out + (9u << 20));

    dim3 blk(256);
    maskpack_kernel<<<dim3((B_ * T_ * T_) / 256), blk, 0, stream>>>(mask, bits);
    cvtx_kernel<<<dim3((B_ * T_ * D_) / 2048), blk, 0, stream>>>(X, Xh);
    wtr_kernel<<<dim3(16, 16, 4), blk, 0, stream>>>(
        Wq, Wk, Wv, Wo, WqT, WkT, WvT, WoT);
    gemm_kernel<<<dim3(D_ / 128, (B_ * T_) / 128, 3), blk, 0, stream>>>(
        Xh, WqT, WkT, WvT, bq, bk, bv, Q, K, Vt);
    attn_split_kernel<<<dim3(B_ * H_ * (T_ / 128) * NSPLIT), blk, 0, stream>>>(
        Q, K, Vt, bits, Op0, Op1, stats);
    combine_kernel<<<dim3((32 * T_) / 32), blk, 0, stream>>>(
        Op0, Op1, stats, comb);
    oproj_kernel<<<dim3(D_ / 64, (B_ * T_) / 128), blk, 0, stream>>>(
        comb, WoT, bo, out);
}